// Round 5
// baseline (434.760 us; speedup 1.0000x reference)
//
#include <hip/hip_runtime.h>
#include <hip/hip_bf16.h>
#include <cstddef>

// NLBasicBlock fused, round 5: barrier-paced 2-stage register prefetch in
// k_nl / k_colstat. R4's pipeline was flattened by the compiler (VGPR=56,
// loads sunk to uses -> serialized L2 round trips). __syncthreads() is a
// scheduling fence loads cannot cross; each stage's 16 loads issue together
// and drain in one vmcnt(0) wait at the barrier.

constexpr int kB = 2, kC = 64, kH = 80, kW = 80, kN = kH * kW;
constexpr float kLOG2E = 1.4426950408889634f;
constexpr float kSHIFT = 28.853900817779268f;  // 20 * log2(e)

typedef __attribute__((ext_vector_type(8))) short short8;
typedef __attribute__((ext_vector_type(4))) float f32x4;

__device__ __forceinline__ int refl(int i, int n) {
  return i < 0 ? -i : (i >= n ? 2 * n - 2 - i : i);
}

__device__ __forceinline__ uint pkbf(float a, float b) {
  union { __hip_bfloat162 h; uint u; } x;
  x.h.x = __float2bfloat16(a);
  x.h.y = __float2bfloat16(b);
  return x.u;
}

#define FMA64(wrp, xv)                                   \
  {                                                      \
    _Pragma("unroll") for (int o_ = 0; o_ < 64; ++o_)    \
        acc[o_] += (wrp)[o_] * (xv);                     \
  }

// ---- weight prep
__global__ void k_prep(const float* __restrict__ w1, const float* __restrict__ w2,
                       const float* __restrict__ wg, const float* __restrict__ wth,
                       const float* __restrict__ wph, const float* __restrict__ wWm,
                       float* __restrict__ w1t, float* __restrict__ w2t,
                       float* __restrict__ wtht, float* __restrict__ wpht,
                       float* __restrict__ wgt, __hip_bfloat16* __restrict__ wWb) {
  int idx = blockIdx.x * 256 + threadIdx.x;
  if (idx < kC * kC * 9) {
    int o = idx / (kC * 9);
    int r = idx % (kC * 9);
    int ci = r / 9, tap = r % 9;
    int d = (ci * 9 + tap) * kC + o;
    w1t[d] = w1[idx];
    w2t[d] = w2[idx];
  }
  if (idx < kC * kC) {
    int o = idx / kC, c = idx % kC;
    int d = c * kC + o;
    wtht[d] = wth[idx];
    wpht[d] = wph[idx];
    wgt[d] = wg[idx];
    wWb[idx] = __float2bfloat16(wWm[idx]);
  }
}

// ---- 3x3 reflect conv (unchanged)
template <int MODE>
__global__ __launch_bounds__(256) void k_conv3x3(
    const float* __restrict__ src, const float* __restrict__ wt,
    const float* __restrict__ alphap, float* __restrict__ dst_raw,
    float* __restrict__ dst_pt) {
  const int tile = blockIdx.x;
  const int cog = blockIdx.y;
  const int b = blockIdx.z;
  const int ty0 = (tile / 5) * 16, tx0 = (tile % 5) * 16;
  const int tid = threadIdx.x;
  const int ty = tid / 16, tx = tid % 16;
  const float alpha = alphap[0];

  __shared__ float lds[32 * 18 * 18];
  float acc[16];
#pragma unroll
  for (int o = 0; o < 16; ++o) acc[o] = 0.f;

  for (int chunk = 0; chunk < 2; ++chunk) {
    const int ci0 = chunk * 32;
    __syncthreads();
    for (int idx = tid; idx < 32 * 324; idx += 256) {
      int cc = idx / 324;
      int r = idx % 324;
      int hh = r / 18, ww = r % 18;
      int gh = refl(ty0 - 1 + hh, kH);
      int gw = refl(tx0 - 1 + ww, kW);
      lds[idx] = src[(((size_t)b * kC + ci0 + cc) * kH + gh) * kW + gw];
    }
    __syncthreads();
    for (int cc = 0; cc < 32; ++cc) {
#pragma unroll
      for (int tap = 0; tap < 9; ++tap) {
        const int dh = tap / 3, dw = tap % 3;
        const float xv = lds[cc * 324 + (ty + dh) * 18 + (tx + dw)];
        const float* wr = wt + ((size_t)(ci0 + cc) * 9 + tap) * kC + cog * 16;
#pragma unroll
        for (int o = 0; o < 16; ++o) acc[o] += wr[o] * xv;
      }
    }
  }

  const int n = (ty0 + ty) * kW + (tx0 + tx);
#pragma unroll
  for (int o = 0; o < 16; ++o) {
    const int co = cog * 16 + o;
    const float v = acc[o];
    const float p = v >= 0.f ? v : alpha * v;
    if (MODE == 0) {
      dst_raw[((size_t)b * kC + co) * kN + n] = v;
      dst_pt[((size_t)b * kN + n) * kC + co] = p;
    } else {
      dst_raw[((size_t)b * kC + co) * kN + n] = p;
    }
  }
}

// ---- three 1x1 convs -> bf16 pixel-major
__global__ __launch_bounds__(64) void k_pw3(const float* __restrict__ pT,
                                            const float* __restrict__ wt3,
                                            __hip_bfloat16* __restrict__ outb) {
  const int m = blockIdx.z, b = blockIdx.y;
  const int n = blockIdx.x * 64 + threadIdx.x;
  const float* wt = wt3 + (size_t)m * kC * kC;
  const float4* p4 = (const float4*)(pT + ((size_t)b * kN + n) * kC);
  float acc[64];
#pragma unroll
  for (int o = 0; o < 64; ++o) acc[o] = 0.f;
#pragma unroll
  for (int cq = 0; cq < 16; ++cq) {
    const float4 t = p4[cq];
    const float* wr = wt + cq * 4 * 64;
    FMA64(wr, t.x);
    FMA64(wr + 64, t.y);
    FMA64(wr + 128, t.z);
    FMA64(wr + 192, t.w);
  }
  uint* d32 = (uint*)(outb + (((size_t)m * kB + b) * kN + n) * kC);
#pragma unroll
  for (int q = 0; q < 32; ++q) d32[q] = pkbf(acc[2 * q], acc[2 * q + 1]);
}

// ---- column sums, barrier-paced 2-stage prefetch, 64-i stages.
__global__ __launch_bounds__(256, 3) void k_colstat(
    const __hip_bfloat16* __restrict__ th, const __hip_bfloat16* __restrict__ ph,
    float* __restrict__ partial) {
  const int b = blockIdx.z, ic = blockIdx.y;
  const int lane = threadIdx.x & 63, w = threadIdx.x >> 6;
  const int il = lane & 15, hi = lane >> 4;
  const int j0 = blockIdx.x * 64 + w * 16;

  const short8 af0 = *(const short8*)&ph[((size_t)b * kN + j0 + il) * kC + hi * 8];
  const short8 af1 = *(const short8*)&ph[((size_t)b * kN + j0 + il) * kC + 32 + hi * 8];
  const __hip_bfloat16* thB = th + (size_t)b * kN * kC;

  float cs[4] = {0.f, 0.f, 0.f, 0.f};
  short8 t0A, t1A, t2A, t3A, t4A, t5A, t6A, t7A;
  short8 t0B, t1B, t2B, t3B, t4B, t5B, t6B, t7B;

#define LOADI64(S, I)                                                         \
  t0##S = *(const short8*)&thB[(size_t)((I) + il) * kC + hi * 8];             \
  t1##S = *(const short8*)&thB[(size_t)((I) + il) * kC + 32 + hi * 8];        \
  t2##S = *(const short8*)&thB[(size_t)((I) + 16 + il) * kC + hi * 8];        \
  t3##S = *(const short8*)&thB[(size_t)((I) + 16 + il) * kC + 32 + hi * 8];   \
  t4##S = *(const short8*)&thB[(size_t)((I) + 32 + il) * kC + hi * 8];        \
  t5##S = *(const short8*)&thB[(size_t)((I) + 32 + il) * kC + 32 + hi * 8];   \
  t6##S = *(const short8*)&thB[(size_t)((I) + 48 + il) * kC + hi * 8];        \
  t7##S = *(const short8*)&thB[(size_t)((I) + 48 + il) * kC + 32 + hi * 8];

#define SUBI(p, q)                                                            \
  {                                                                           \
    f32x4 s = {0.f, 0.f, 0.f, 0.f};                                           \
    s = __builtin_amdgcn_mfma_f32_16x16x32_bf16(af0, p, s, 0, 0, 0);          \
    s = __builtin_amdgcn_mfma_f32_16x16x32_bf16(af1, q, s, 0, 0, 0);          \
    _Pragma("unroll") for (int r = 0; r < 4; ++r)                             \
        cs[r] += exp2f(fmaf(s[r], kLOG2E, -kSHIFT));                          \
  }

#define COMPI64(S)                                                            \
  SUBI(t0##S, t1##S) SUBI(t2##S, t3##S) SUBI(t4##S, t5##S) SUBI(t6##S, t7##S)

  int i = ic * (kN / 4);  // 1600 i's = 25 stages of 64
  LOADI64(A, i)
  for (int s = 0; s < 12; ++s, i += 128) {
    LOADI64(B, i + 64)
    __syncthreads();
    COMPI64(A)
    LOADI64(A, i + 128)
    __syncthreads();
    COMPI64(B)
  }
  COMPI64(A)
#undef LOADI64
#undef SUBI
#undef COMPI64

#pragma unroll
  for (int r = 0; r < 4; ++r) {
    cs[r] += __shfl_xor(cs[r], 1);
    cs[r] += __shfl_xor(cs[r], 2);
    cs[r] += __shfl_xor(cs[r], 4);
    cs[r] += __shfl_xor(cs[r], 8);
  }
  if (il == 0) {
    float* p = partial + ((size_t)(b * 4 + ic)) * kN + j0 + hi * 4;
#pragma unroll
    for (int r = 0; r < 4; ++r) p[r] = cs[r];
  }
}

// ---- gT[b][c][j] = bf16( g[b][j][c] * 1/colsum[b][j] )
__global__ __launch_bounds__(256) void k_gscale(
    const __hip_bfloat16* __restrict__ gb, const float* __restrict__ partial,
    __hip_bfloat16* __restrict__ gT) {
  const int b = blockIdx.y;
  const int j0 = blockIdx.x * 64;
  const int t = threadIdx.x;
  __shared__ ushort tile[64][66];
  __shared__ float rsv[64];
  if (t < 64) {
    const int j = j0 + t;
    float cs = partial[(size_t)(b * 4 + 0) * kN + j] +
               partial[(size_t)(b * 4 + 1) * kN + j] +
               partial[(size_t)(b * 4 + 2) * kN + j] +
               partial[(size_t)(b * 4 + 3) * kN + j];
    rsv[t] = 1.0f / cs;
  }
  {
    const int jl = t >> 2, cseg = (t & 3) * 16;
    const ushort* src = (const ushort*)&gb[((size_t)b * kN + j0 + jl) * kC + cseg];
    union { short8 v; ushort u[8]; } u0, u1;
    u0.v = *(const short8*)src;
    u1.v = *(const short8*)(src + 8);
#pragma unroll
    for (int k = 0; k < 8; ++k) {
      tile[jl][cseg + k] = u0.u[k];
      tile[jl][cseg + 8 + k] = u1.u[k];
    }
  }
  __syncthreads();
  const int c = t >> 2, jseg = (t & 3) * 16;
  union { short8 v; ushort u[8]; } o0, o1;
#pragma unroll
  for (int k = 0; k < 16; ++k) {
    const int j = jseg + k;
    const float gv = __uint_as_float((uint)tile[j][c] << 16);
    union { __hip_bfloat16 h; ushort us; } cv;
    cv.h = __float2bfloat16(gv * rsv[j]);
    if (k < 8) o0.u[k] = cv.us; else o1.u[k - 8] = cv.us;
  }
  short8* dst = (short8*)&gT[((size_t)b * kC + c) * kN + j0 + jseg];
  dst[0] = o0.v;
  dst[1] = o1.v;
}

// ---- fused pass B + W_y + residuals, barrier-paced 2-stage, 64-j stages.
__global__ __launch_bounds__(256, 3) void k_nl(
    const __hip_bfloat16* __restrict__ th, const __hip_bfloat16* __restrict__ ph,
    const __hip_bfloat16* __restrict__ gT, const __hip_bfloat16* __restrict__ wWb,
    const float* __restrict__ x1, const float* __restrict__ alphap,
    float* __restrict__ z) {
  const int b = blockIdx.y;
  const int lane = threadIdx.x & 63, w = threadIdx.x >> 6;
  const int il = lane & 15, hi = lane >> 4;
  const int i0 = blockIdx.x * 16;
  const int jbase = ((il >> 2) << 3) + (il & 3);  // sigma(row=il)

  __shared__ float red[4][16][64];
  __shared__ ushort ytile[16 * 72];

  const short8 tb0 = *(const short8*)&th[((size_t)b * kN + i0 + il) * kC + hi * 8];
  const short8 tb1 = *(const short8*)&th[((size_t)b * kN + i0 + il) * kC + 32 + hi * 8];

  f32x4 accy0 = {0.f, 0.f, 0.f, 0.f};
  f32x4 accy1 = {0.f, 0.f, 0.f, 0.f};
  f32x4 accy2 = {0.f, 0.f, 0.f, 0.f};
  f32x4 accy3 = {0.f, 0.f, 0.f, 0.f};

  const __hip_bfloat16* phB = ph + (size_t)b * kN * kC;
  const __hip_bfloat16* gTB = gT + (size_t)b * kC * kN;

  short8 pa0A, pa1A, pa2A, pa3A, pa4A, pa5A, pa6A, pa7A;
  short8 ga0A, ga1A, ga2A, ga3A, ga4A, ga5A, ga6A, ga7A;
  short8 pa0B, pa1B, pa2B, pa3B, pa4B, pa5B, pa6B, pa7B;
  short8 ga0B, ga1B, ga2B, ga3B, ga4B, ga5B, ga6B, ga7B;

#define LOADJ64(S, JG)                                                        \
  {                                                                           \
    const size_t r0_ = (size_t)((JG) + jbase) * kC;                           \
    const size_t r1_ = (size_t)((JG) + jbase + 4) * kC;                       \
    const size_t r2_ = (size_t)((JG) + 32 + jbase) * kC;                      \
    const size_t r3_ = (size_t)((JG) + 36 + jbase) * kC;                      \
    pa0##S = *(const short8*)&phB[r0_ + hi * 8];                              \
    pa1##S = *(const short8*)&phB[r0_ + 32 + hi * 8];                         \
    pa2##S = *(const short8*)&phB[r1_ + hi * 8];                              \
    pa3##S = *(const short8*)&phB[r1_ + 32 + hi * 8];                         \
    pa4##S = *(const short8*)&phB[r2_ + hi * 8];                              \
    pa5##S = *(const short8*)&phB[r2_ + 32 + hi * 8];                         \
    pa6##S = *(const short8*)&phB[r3_ + hi * 8];                              \
    pa7##S = *(const short8*)&phB[r3_ + 32 + hi * 8];                         \
    ga0##S = *(const short8*)&gTB[(size_t)il * kN + (JG) + hi * 8];           \
    ga1##S = *(const short8*)&gTB[(size_t)(16 + il) * kN + (JG) + hi * 8];    \
    ga2##S = *(const short8*)&gTB[(size_t)(32 + il) * kN + (JG) + hi * 8];    \
    ga3##S = *(const short8*)&gTB[(size_t)(48 + il) * kN + (JG) + hi * 8];    \
    ga4##S = *(const short8*)&gTB[(size_t)il * kN + (JG) + 32 + hi * 8];      \
    ga5##S = *(const short8*)&gTB[(size_t)(16 + il) * kN + (JG) + 32 + hi * 8]; \
    ga6##S = *(const short8*)&gTB[(size_t)(32 + il) * kN + (JG) + 32 + hi * 8]; \
    ga7##S = *(const short8*)&gTB[(size_t)(48 + il) * kN + (JG) + 32 + hi * 8]; \
  }

#define COMPJ64(S)                                                            \
  {                                                                           \
    f32x4 s0 = {0.f, 0.f, 0.f, 0.f};                                          \
    f32x4 s1 = {0.f, 0.f, 0.f, 0.f};                                          \
    f32x4 s2 = {0.f, 0.f, 0.f, 0.f};                                          \
    f32x4 s3 = {0.f, 0.f, 0.f, 0.f};                                          \
    s0 = __builtin_amdgcn_mfma_f32_16x16x32_bf16(pa0##S, tb0, s0, 0, 0, 0);   \
    s0 = __builtin_amdgcn_mfma_f32_16x16x32_bf16(pa1##S, tb1, s0, 0, 0, 0);   \
    s1 = __builtin_amdgcn_mfma_f32_16x16x32_bf16(pa2##S, tb0, s1, 0, 0, 0);   \
    s1 = __builtin_amdgcn_mfma_f32_16x16x32_bf16(pa3##S, tb1, s1, 0, 0, 0);   \
    s2 = __builtin_amdgcn_mfma_f32_16x16x32_bf16(pa4##S, tb0, s2, 0, 0, 0);   \
    s2 = __builtin_amdgcn_mfma_f32_16x16x32_bf16(pa5##S, tb1, s2, 0, 0, 0);   \
    s3 = __builtin_amdgcn_mfma_f32_16x16x32_bf16(pa6##S, tb0, s3, 0, 0, 0);   \
    s3 = __builtin_amdgcn_mfma_f32_16x16x32_bf16(pa7##S, tb1, s3, 0, 0, 0);   \
    short8 pb0, pb1;                                                          \
    {                                                                         \
      uint* pw_ = (uint*)&pb0;                                                \
      pw_[0] = pkbf(exp2f(fmaf(s0[0], kLOG2E, -kSHIFT)),                      \
                    exp2f(fmaf(s0[1], kLOG2E, -kSHIFT)));                     \
      pw_[1] = pkbf(exp2f(fmaf(s0[2], kLOG2E, -kSHIFT)),                      \
                    exp2f(fmaf(s0[3], kLOG2E, -kSHIFT)));                     \
      pw_[2] = pkbf(exp2f(fmaf(s1[0], kLOG2E, -kSHIFT)),                      \
                    exp2f(fmaf(s1[1], kLOG2E, -kSHIFT)));                     \
      pw_[3] = pkbf(exp2f(fmaf(s1[2], kLOG2E, -kSHIFT)),                      \
                    exp2f(fmaf(s1[3], kLOG2E, -kSHIFT)));                     \
    }                                                                         \
    accy0 = __builtin_amdgcn_mfma_f32_16x16x32_bf16(ga0##S, pb0, accy0, 0, 0, 0); \
    accy1 = __builtin_amdgcn_mfma_f32_16x16x32_bf16(ga1##S, pb0, accy1, 0, 0, 0); \
    {                                                                         \
      uint* pw_ = (uint*)&pb1;                                                \
      pw_[0] = pkbf(exp2f(fmaf(s2[0], kLOG2E, -kSHIFT)),                      \
                    exp2f(fmaf(s2[1], kLOG2E, -kSHIFT)));                     \
      pw_[1] = pkbf(exp2f(fmaf(s2[2], kLOG2E, -kSHIFT)),                      \
                    exp2f(fmaf(s2[3], kLOG2E, -kSHIFT)));                     \
      pw_[2] = pkbf(exp2f(fmaf(s3[0], kLOG2E, -kSHIFT)),                      \
                    exp2f(fmaf(s3[1], kLOG2E, -kSHIFT)));                     \
      pw_[3] = pkbf(exp2f(fmaf(s3[2], kLOG2E, -kSHIFT)),                      \
                    exp2f(fmaf(s3[3], kLOG2E, -kSHIFT)));                     \
    }                                                                         \
    accy2 = __builtin_amdgcn_mfma_f32_16x16x32_bf16(ga2##S, pb0, accy2, 0, 0, 0); \
    accy3 = __builtin_amdgcn_mfma_f32_16x16x32_bf16(ga3##S, pb0, accy3, 0, 0, 0); \
    accy0 = __builtin_amdgcn_mfma_f32_16x16x32_bf16(ga4##S, pb1, accy0, 0, 0, 0); \
    accy1 = __builtin_amdgcn_mfma_f32_16x16x32_bf16(ga5##S, pb1, accy1, 0, 0, 0); \
    accy2 = __builtin_amdgcn_mfma_f32_16x16x32_bf16(ga6##S, pb1, accy2, 0, 0, 0); \
    accy3 = __builtin_amdgcn_mfma_f32_16x16x32_bf16(ga7##S, pb1, accy3, 0, 0, 0); \
  }

  int jg = w * (kN / 4);  // 1600 j's = 25 stages of 64
  LOADJ64(A, jg)
  for (int s = 0; s < 12; ++s, jg += 128) {
    LOADJ64(B, jg + 64)
    __syncthreads();
    COMPJ64(A)
    LOADJ64(A, jg + 128)
    __syncthreads();
    COMPJ64(B)
  }
  COMPJ64(A)
#undef LOADJ64
#undef COMPJ64

  {
    const f32x4* accp[4] = {&accy0, &accy1, &accy2, &accy3};
#pragma unroll
    for (int ct = 0; ct < 4; ++ct)
#pragma unroll
      for (int r = 0; r < 4; ++r) red[w][ct * 4 + r][lane] = (*accp[ct])[r];
  }
  __syncthreads();
  if (w == 0) {
#pragma unroll
    for (int k = 0; k < 16; k += 2) {
      const float va = red[0][k][lane] + red[1][k][lane] + red[2][k][lane] +
                       red[3][k][lane];
      const float vb = red[0][k + 1][lane] + red[1][k + 1][lane] +
                       red[2][k + 1][lane] + red[3][k + 1][lane];
      const int c0 = ((k >> 2) << 4) + hi * 4 + (k & 3);
      *(uint*)&ytile[il * 72 + c0] = pkbf(va, vb);
    }
  }
  __syncthreads();

  const short8 af0 = *(const short8*)&wWb[(size_t)(w * 16 + il) * kC + hi * 8];
  const short8 af1 = *(const short8*)&wWb[(size_t)(w * 16 + il) * kC + 32 + hi * 8];
  const short8 by0 = *(const short8*)&ytile[il * 72 + hi * 8];
  const short8 by1 = *(const short8*)&ytile[il * 72 + 32 + hi * 8];
  f32x4 o4 = {0.f, 0.f, 0.f, 0.f};
  o4 = __builtin_amdgcn_mfma_f32_16x16x32_bf16(af0, by0, o4, 0, 0, 0);
  o4 = __builtin_amdgcn_mfma_f32_16x16x32_bf16(af1, by1, o4, 0, 0, 0);
  const float alpha = alphap[0];
#pragma unroll
  for (int r = 0; r < 4; ++r) {
    const int o = w * 16 + hi * 4 + r;
    const size_t idx = ((size_t)b * kC + o) * kN + i0 + il;
    const float xv = x1[idx];
    const float p = xv >= 0.f ? xv : alpha * xv;
    z[idx] = o4[r] + p + xv;
  }
}

extern "C" void kernel_launch(void* const* d_in, const int* in_sizes, int n_in,
                              void* d_out, int out_size, void* d_ws, size_t ws_size,
                              hipStream_t stream) {
  const float* x      = (const float*)d_in[0];
  const float* w1     = (const float*)d_in[1];
  const float* w2     = (const float*)d_in[2];
  const float* wg     = (const float*)d_in[3];
  const float* wth    = (const float*)d_in[4];
  const float* wph    = (const float*)d_in[5];
  const float* wWm    = (const float*)d_in[6];
  const float* alphap = (const float*)d_in[7];
  float* out = (float*)d_out;

  const size_t SZ = (size_t)kB * kC * kN;  // 819200 elements
  float* x1 = (float*)d_ws;                          // [B][C][N] f32
  float* pT = x1 + SZ;                               // [B][N][C] f32; reused as z
  __hip_bfloat16* thb = (__hip_bfloat16*)(pT + SZ);  // [B][N][C] bf16
  __hip_bfloat16* phb = thb + SZ;
  __hip_bfloat16* gb  = phb + SZ;
  __hip_bfloat16* gT  = gb + SZ;                     // [B][C][N] bf16 (rs-scaled)
  float* partial = (float*)(gT + SZ);                // [B][4][N] f32
  float* w1t = partial + (size_t)kB * 4 * kN;
  float* w2t = w1t + kC * kC * 9;
  float* wt3 = w2t + kC * kC * 9;
  __hip_bfloat16* wWb = (__hip_bfloat16*)(wt3 + 3 * kC * kC);
  float* z = pT;  // pT dead after k_pw3

  k_prep<<<144, 256, 0, stream>>>(w1, w2, wg, wth, wph, wWm, w1t, w2t,
                                  wt3, wt3 + kC * kC, wt3 + 2 * kC * kC, wWb);
  k_conv3x3<0><<<dim3(25, 4, kB), 256, 0, stream>>>(x, w1t, alphap, x1, pT);
  k_pw3<<<dim3(kN / 64, kB, 3), 64, 0, stream>>>(pT, wt3, thb);
  k_colstat<<<dim3(kN / 64, 4, kB), 256, 0, stream>>>(thb, phb, partial);
  k_gscale<<<dim3(kN / 64, kB), 256, 0, stream>>>(gb, partial, gT);
  k_nl<<<dim3(kN / 16, kB), 256, 0, stream>>>(thb, phb, gT, wWb, x1, alphap, z);
  k_conv3x3<1><<<dim3(25, 4, kB), 256, 0, stream>>>(z, w2t, alphap, out, nullptr);
}

// Round 6
// 433.952 us; speedup vs baseline: 1.0019x; 1.0019x over previous
//
#include <hip/hip_runtime.h>
#include <hip/hip_bf16.h>
#include <cstddef>

// NLBasicBlock fused, round 6: pin the 2-stage register prefetch with
// __builtin_amdgcn_sched_barrier(0) (compile-time fence the machine scheduler
// cannot cross) instead of __syncthreads (which does NOT order global loads).
// k_nl gets __launch_bounds__(256,2) so RA has budget (~256 VGPR) to hold
// both stages; R5's (256,3) cap (~170) forced re-serialization.

constexpr int kB = 2, kC = 64, kH = 80, kW = 80, kN = kH * kW;
constexpr float kLOG2E = 1.4426950408889634f;
constexpr float kSHIFT = 28.853900817779268f;  // 20 * log2(e)

typedef __attribute__((ext_vector_type(8))) short short8;
typedef __attribute__((ext_vector_type(4))) float f32x4;

__device__ __forceinline__ int refl(int i, int n) {
  return i < 0 ? -i : (i >= n ? 2 * n - 2 - i : i);
}

__device__ __forceinline__ uint pkbf(float a, float b) {
  union { __hip_bfloat162 h; uint u; } x;
  x.h.x = __float2bfloat16(a);
  x.h.y = __float2bfloat16(b);
  return x.u;
}

#define SBAR() __builtin_amdgcn_sched_barrier(0)

#define FMA64(wrp, xv)                                   \
  {                                                      \
    _Pragma("unroll") for (int o_ = 0; o_ < 64; ++o_)    \
        acc[o_] += (wrp)[o_] * (xv);                     \
  }

// ---- weight prep
__global__ void k_prep(const float* __restrict__ w1, const float* __restrict__ w2,
                       const float* __restrict__ wg, const float* __restrict__ wth,
                       const float* __restrict__ wph, const float* __restrict__ wWm,
                       float* __restrict__ w1t, float* __restrict__ w2t,
                       float* __restrict__ wtht, float* __restrict__ wpht,
                       float* __restrict__ wgt, __hip_bfloat16* __restrict__ wWb) {
  int idx = blockIdx.x * 256 + threadIdx.x;
  if (idx < kC * kC * 9) {
    int o = idx / (kC * 9);
    int r = idx % (kC * 9);
    int ci = r / 9, tap = r % 9;
    int d = (ci * 9 + tap) * kC + o;
    w1t[d] = w1[idx];
    w2t[d] = w2[idx];
  }
  if (idx < kC * kC) {
    int o = idx / kC, c = idx % kC;
    int d = c * kC + o;
    wtht[d] = wth[idx];
    wpht[d] = wph[idx];
    wgt[d] = wg[idx];
    wWb[idx] = __float2bfloat16(wWm[idx]);
  }
}

// ---- 3x3 reflect conv (unchanged)
template <int MODE>
__global__ __launch_bounds__(256) void k_conv3x3(
    const float* __restrict__ src, const float* __restrict__ wt,
    const float* __restrict__ alphap, float* __restrict__ dst_raw,
    float* __restrict__ dst_pt) {
  const int tile = blockIdx.x;
  const int cog = blockIdx.y;
  const int b = blockIdx.z;
  const int ty0 = (tile / 5) * 16, tx0 = (tile % 5) * 16;
  const int tid = threadIdx.x;
  const int ty = tid / 16, tx = tid % 16;
  const float alpha = alphap[0];

  __shared__ float lds[32 * 18 * 18];
  float acc[16];
#pragma unroll
  for (int o = 0; o < 16; ++o) acc[o] = 0.f;

  for (int chunk = 0; chunk < 2; ++chunk) {
    const int ci0 = chunk * 32;
    __syncthreads();
    for (int idx = tid; idx < 32 * 324; idx += 256) {
      int cc = idx / 324;
      int r = idx % 324;
      int hh = r / 18, ww = r % 18;
      int gh = refl(ty0 - 1 + hh, kH);
      int gw = refl(tx0 - 1 + ww, kW);
      lds[idx] = src[(((size_t)b * kC + ci0 + cc) * kH + gh) * kW + gw];
    }
    __syncthreads();
    for (int cc = 0; cc < 32; ++cc) {
#pragma unroll
      for (int tap = 0; tap < 9; ++tap) {
        const int dh = tap / 3, dw = tap % 3;
        const float xv = lds[cc * 324 + (ty + dh) * 18 + (tx + dw)];
        const float* wr = wt + ((size_t)(ci0 + cc) * 9 + tap) * kC + cog * 16;
#pragma unroll
        for (int o = 0; o < 16; ++o) acc[o] += wr[o] * xv;
      }
    }
  }

  const int n = (ty0 + ty) * kW + (tx0 + tx);
#pragma unroll
  for (int o = 0; o < 16; ++o) {
    const int co = cog * 16 + o;
    const float v = acc[o];
    const float p = v >= 0.f ? v : alpha * v;
    if (MODE == 0) {
      dst_raw[((size_t)b * kC + co) * kN + n] = v;
      dst_pt[((size_t)b * kN + n) * kC + co] = p;
    } else {
      dst_raw[((size_t)b * kC + co) * kN + n] = p;
    }
  }
}

// ---- three 1x1 convs -> bf16 pixel-major
__global__ __launch_bounds__(64) void k_pw3(const float* __restrict__ pT,
                                            const float* __restrict__ wt3,
                                            __hip_bfloat16* __restrict__ outb) {
  const int m = blockIdx.z, b = blockIdx.y;
  const int n = blockIdx.x * 64 + threadIdx.x;
  const float* wt = wt3 + (size_t)m * kC * kC;
  const float4* p4 = (const float4*)(pT + ((size_t)b * kN + n) * kC);
  float acc[64];
#pragma unroll
  for (int o = 0; o < 64; ++o) acc[o] = 0.f;
#pragma unroll
  for (int cq = 0; cq < 16; ++cq) {
    const float4 t = p4[cq];
    const float* wr = wt + cq * 4 * 64;
    FMA64(wr, t.x);
    FMA64(wr + 64, t.y);
    FMA64(wr + 128, t.z);
    FMA64(wr + 192, t.w);
  }
  uint* d32 = (uint*)(outb + (((size_t)m * kB + b) * kN + n) * kC);
#pragma unroll
  for (int q = 0; q < 32; ++q) d32[q] = pkbf(acc[2 * q], acc[2 * q + 1]);
}

// ---- column sums, sched_barrier-pinned 2-stage prefetch, 64-i stages.
__global__ __launch_bounds__(256, 3) void k_colstat(
    const __hip_bfloat16* __restrict__ th, const __hip_bfloat16* __restrict__ ph,
    float* __restrict__ partial) {
  const int b = blockIdx.z, ic = blockIdx.y;
  const int lane = threadIdx.x & 63;
  const int w = threadIdx.x >> 6;
  const int il = lane & 15, hi = lane >> 4;
  const int j0 = blockIdx.x * 64 + w * 16;

  const short8 af0 = *(const short8*)&ph[((size_t)b * kN + j0 + il) * kC + hi * 8];
  const short8 af1 = *(const short8*)&ph[((size_t)b * kN + j0 + il) * kC + 32 + hi * 8];
  const __hip_bfloat16* thB = th + (size_t)b * kN * kC;

  float cs[4] = {0.f, 0.f, 0.f, 0.f};
  short8 t0A, t1A, t2A, t3A, t4A, t5A, t6A, t7A;
  short8 t0B, t1B, t2B, t3B, t4B, t5B, t6B, t7B;

#define LOADI64(S, I)                                                         \
  t0##S = *(const short8*)&thB[(size_t)((I) + il) * kC + hi * 8];             \
  t1##S = *(const short8*)&thB[(size_t)((I) + il) * kC + 32 + hi * 8];        \
  t2##S = *(const short8*)&thB[(size_t)((I) + 16 + il) * kC + hi * 8];        \
  t3##S = *(const short8*)&thB[(size_t)((I) + 16 + il) * kC + 32 + hi * 8];   \
  t4##S = *(const short8*)&thB[(size_t)((I) + 32 + il) * kC + hi * 8];        \
  t5##S = *(const short8*)&thB[(size_t)((I) + 32 + il) * kC + 32 + hi * 8];   \
  t6##S = *(const short8*)&thB[(size_t)((I) + 48 + il) * kC + hi * 8];        \
  t7##S = *(const short8*)&thB[(size_t)((I) + 48 + il) * kC + 32 + hi * 8];

#define SUBI(p, q)                                                            \
  {                                                                           \
    f32x4 s = {0.f, 0.f, 0.f, 0.f};                                           \
    s = __builtin_amdgcn_mfma_f32_16x16x32_bf16(af0, p, s, 0, 0, 0);          \
    s = __builtin_amdgcn_mfma_f32_16x16x32_bf16(af1, q, s, 0, 0, 0);          \
    _Pragma("unroll") for (int r = 0; r < 4; ++r)                             \
        cs[r] += exp2f(fmaf(s[r], kLOG2E, -kSHIFT));                          \
  }

#define COMPI64(S)                                                            \
  SUBI(t0##S, t1##S) SUBI(t2##S, t3##S) SUBI(t4##S, t5##S) SUBI(t6##S, t7##S)

  int i = ic * (kN / 4);  // 1600 i's = 25 stages of 64
  LOADI64(A, i)
  for (int s = 0; s < 12; ++s, i += 128) {
    LOADI64(B, i + 64)
    SBAR();
    COMPI64(A)
    LOADI64(A, i + 128)
    SBAR();
    COMPI64(B)
  }
  COMPI64(A)
#undef LOADI64
#undef SUBI
#undef COMPI64

#pragma unroll
  for (int r = 0; r < 4; ++r) {
    cs[r] += __shfl_xor(cs[r], 1);
    cs[r] += __shfl_xor(cs[r], 2);
    cs[r] += __shfl_xor(cs[r], 4);
    cs[r] += __shfl_xor(cs[r], 8);
  }
  if (il == 0) {
    float* p = partial + ((size_t)(b * 4 + ic)) * kN + j0 + hi * 4;
#pragma unroll
    for (int r = 0; r < 4; ++r) p[r] = cs[r];
  }
}

// ---- gT[b][c][j] = bf16( g[b][j][c] * 1/colsum[b][j] )
__global__ __launch_bounds__(256) void k_gscale(
    const __hip_bfloat16* __restrict__ gb, const float* __restrict__ partial,
    __hip_bfloat16* __restrict__ gT) {
  const int b = blockIdx.y;
  const int j0 = blockIdx.x * 64;
  const int t = threadIdx.x;
  __shared__ ushort tile[64][66];
  __shared__ float rsv[64];
  if (t < 64) {
    const int j = j0 + t;
    float cs = partial[(size_t)(b * 4 + 0) * kN + j] +
               partial[(size_t)(b * 4 + 1) * kN + j] +
               partial[(size_t)(b * 4 + 2) * kN + j] +
               partial[(size_t)(b * 4 + 3) * kN + j];
    rsv[t] = 1.0f / cs;
  }
  {
    const int jl = t >> 2, cseg = (t & 3) * 16;
    const ushort* src = (const ushort*)&gb[((size_t)b * kN + j0 + jl) * kC + cseg];
    union { short8 v; ushort u[8]; } u0, u1;
    u0.v = *(const short8*)src;
    u1.v = *(const short8*)(src + 8);
#pragma unroll
    for (int k = 0; k < 8; ++k) {
      tile[jl][cseg + k] = u0.u[k];
      tile[jl][cseg + 8 + k] = u1.u[k];
    }
  }
  __syncthreads();
  const int c = t >> 2, jseg = (t & 3) * 16;
  union { short8 v; ushort u[8]; } o0, o1;
#pragma unroll
  for (int k = 0; k < 16; ++k) {
    const int j = jseg + k;
    const float gv = __uint_as_float((uint)tile[j][c] << 16);
    union { __hip_bfloat16 h; ushort us; } cv;
    cv.h = __float2bfloat16(gv * rsv[j]);
    if (k < 8) o0.u[k] = cv.us; else o1.u[k - 8] = cv.us;
  }
  short8* dst = (short8*)&gT[((size_t)b * kC + c) * kN + j0 + jseg];
  dst[0] = o0.v;
  dst[1] = o1.v;
}

// ---- fused pass B + W_y + residuals, sched_barrier-pinned 2-stage, 64-j.
__global__ __launch_bounds__(256, 2) void k_nl(
    const __hip_bfloat16* __restrict__ th, const __hip_bfloat16* __restrict__ ph,
    const __hip_bfloat16* __restrict__ gT, const __hip_bfloat16* __restrict__ wWb,
    const float* __restrict__ x1, const float* __restrict__ alphap,
    float* __restrict__ z) {
  const int b = blockIdx.y;
  const int lane = threadIdx.x & 63, w = threadIdx.x >> 6;
  const int il = lane & 15, hi = lane >> 4;
  const int i0 = blockIdx.x * 16;
  const int jbase = ((il >> 2) << 3) + (il & 3);  // sigma(row=il)

  __shared__ float red[4][16][64];
  __shared__ ushort ytile[16 * 72];

  const short8 tb0 = *(const short8*)&th[((size_t)b * kN + i0 + il) * kC + hi * 8];
  const short8 tb1 = *(const short8*)&th[((size_t)b * kN + i0 + il) * kC + 32 + hi * 8];

  f32x4 accy0 = {0.f, 0.f, 0.f, 0.f};
  f32x4 accy1 = {0.f, 0.f, 0.f, 0.f};
  f32x4 accy2 = {0.f, 0.f, 0.f, 0.f};
  f32x4 accy3 = {0.f, 0.f, 0.f, 0.f};

  const __hip_bfloat16* phB = ph + (size_t)b * kN * kC;
  const __hip_bfloat16* gTB = gT + (size_t)b * kC * kN;

  short8 pa0A, pa1A, pa2A, pa3A, pa4A, pa5A, pa6A, pa7A;
  short8 ga0A, ga1A, ga2A, ga3A, ga4A, ga5A, ga6A, ga7A;
  short8 pa0B, pa1B, pa2B, pa3B, pa4B, pa5B, pa6B, pa7B;
  short8 ga0B, ga1B, ga2B, ga3B, ga4B, ga5B, ga6B, ga7B;

#define LOADJ64(S, JG)                                                        \
  {                                                                           \
    const size_t r0_ = (size_t)((JG) + jbase) * kC;                           \
    const size_t r1_ = (size_t)((JG) + jbase + 4) * kC;                       \
    const size_t r2_ = (size_t)((JG) + 32 + jbase) * kC;                      \
    const size_t r3_ = (size_t)((JG) + 36 + jbase) * kC;                      \
    pa0##S = *(const short8*)&phB[r0_ + hi * 8];                              \
    pa1##S = *(const short8*)&phB[r0_ + 32 + hi * 8];                         \
    pa2##S = *(const short8*)&phB[r1_ + hi * 8];                              \
    pa3##S = *(const short8*)&phB[r1_ + 32 + hi * 8];                         \
    pa4##S = *(const short8*)&phB[r2_ + hi * 8];                              \
    pa5##S = *(const short8*)&phB[r2_ + 32 + hi * 8];                         \
    pa6##S = *(const short8*)&phB[r3_ + hi * 8];                              \
    pa7##S = *(const short8*)&phB[r3_ + 32 + hi * 8];                         \
    ga0##S = *(const short8*)&gTB[(size_t)il * kN + (JG) + hi * 8];           \
    ga1##S = *(const short8*)&gTB[(size_t)(16 + il) * kN + (JG) + hi * 8];    \
    ga2##S = *(const short8*)&gTB[(size_t)(32 + il) * kN + (JG) + hi * 8];    \
    ga3##S = *(const short8*)&gTB[(size_t)(48 + il) * kN + (JG) + hi * 8];    \
    ga4##S = *(const short8*)&gTB[(size_t)il * kN + (JG) + 32 + hi * 8];      \
    ga5##S = *(const short8*)&gTB[(size_t)(16 + il) * kN + (JG) + 32 + hi * 8]; \
    ga6##S = *(const short8*)&gTB[(size_t)(32 + il) * kN + (JG) + 32 + hi * 8]; \
    ga7##S = *(const short8*)&gTB[(size_t)(48 + il) * kN + (JG) + 32 + hi * 8]; \
  }

#define COMPJ64(S)                                                            \
  {                                                                           \
    f32x4 s0 = {0.f, 0.f, 0.f, 0.f};                                          \
    f32x4 s1 = {0.f, 0.f, 0.f, 0.f};                                          \
    f32x4 s2 = {0.f, 0.f, 0.f, 0.f};                                          \
    f32x4 s3 = {0.f, 0.f, 0.f, 0.f};                                          \
    s0 = __builtin_amdgcn_mfma_f32_16x16x32_bf16(pa0##S, tb0, s0, 0, 0, 0);   \
    s0 = __builtin_amdgcn_mfma_f32_16x16x32_bf16(pa1##S, tb1, s0, 0, 0, 0);   \
    s1 = __builtin_amdgcn_mfma_f32_16x16x32_bf16(pa2##S, tb0, s1, 0, 0, 0);   \
    s1 = __builtin_amdgcn_mfma_f32_16x16x32_bf16(pa3##S, tb1, s1, 0, 0, 0);   \
    s2 = __builtin_amdgcn_mfma_f32_16x16x32_bf16(pa4##S, tb0, s2, 0, 0, 0);   \
    s2 = __builtin_amdgcn_mfma_f32_16x16x32_bf16(pa5##S, tb1, s2, 0, 0, 0);   \
    s3 = __builtin_amdgcn_mfma_f32_16x16x32_bf16(pa6##S, tb0, s3, 0, 0, 0);   \
    s3 = __builtin_amdgcn_mfma_f32_16x16x32_bf16(pa7##S, tb1, s3, 0, 0, 0);   \
    short8 pb0, pb1;                                                          \
    {                                                                         \
      uint* pw_ = (uint*)&pb0;                                                \
      pw_[0] = pkbf(exp2f(fmaf(s0[0], kLOG2E, -kSHIFT)),                      \
                    exp2f(fmaf(s0[1], kLOG2E, -kSHIFT)));                     \
      pw_[1] = pkbf(exp2f(fmaf(s0[2], kLOG2E, -kSHIFT)),                      \
                    exp2f(fmaf(s0[3], kLOG2E, -kSHIFT)));                     \
      pw_[2] = pkbf(exp2f(fmaf(s1[0], kLOG2E, -kSHIFT)),                      \
                    exp2f(fmaf(s1[1], kLOG2E, -kSHIFT)));                     \
      pw_[3] = pkbf(exp2f(fmaf(s1[2], kLOG2E, -kSHIFT)),                      \
                    exp2f(fmaf(s1[3], kLOG2E, -kSHIFT)));                     \
    }                                                                         \
    accy0 = __builtin_amdgcn_mfma_f32_16x16x32_bf16(ga0##S, pb0, accy0, 0, 0, 0); \
    accy1 = __builtin_amdgcn_mfma_f32_16x16x32_bf16(ga1##S, pb0, accy1, 0, 0, 0); \
    {                                                                         \
      uint* pw_ = (uint*)&pb1;                                                \
      pw_[0] = pkbf(exp2f(fmaf(s2[0], kLOG2E, -kSHIFT)),                      \
                    exp2f(fmaf(s2[1], kLOG2E, -kSHIFT)));                     \
      pw_[1] = pkbf(exp2f(fmaf(s2[2], kLOG2E, -kSHIFT)),                      \
                    exp2f(fmaf(s2[3], kLOG2E, -kSHIFT)));                     \
      pw_[2] = pkbf(exp2f(fmaf(s3[0], kLOG2E, -kSHIFT)),                      \
                    exp2f(fmaf(s3[1], kLOG2E, -kSHIFT)));                     \
      pw_[3] = pkbf(exp2f(fmaf(s3[2], kLOG2E, -kSHIFT)),                      \
                    exp2f(fmaf(s3[3], kLOG2E, -kSHIFT)));                     \
    }                                                                         \
    accy2 = __builtin_amdgcn_mfma_f32_16x16x32_bf16(ga2##S, pb0, accy2, 0, 0, 0); \
    accy3 = __builtin_amdgcn_mfma_f32_16x16x32_bf16(ga3##S, pb0, accy3, 0, 0, 0); \
    accy0 = __builtin_amdgcn_mfma_f32_16x16x32_bf16(ga4##S, pb1, accy0, 0, 0, 0); \
    accy1 = __builtin_amdgcn_mfma_f32_16x16x32_bf16(ga5##S, pb1, accy1, 0, 0, 0); \
    accy2 = __builtin_amdgcn_mfma_f32_16x16x32_bf16(ga6##S, pb1, accy2, 0, 0, 0); \
    accy3 = __builtin_amdgcn_mfma_f32_16x16x32_bf16(ga7##S, pb1, accy3, 0, 0, 0); \
  }

  int jg = w * (kN / 4);  // 1600 j's = 25 stages of 64
  LOADJ64(A, jg)
  for (int s = 0; s < 12; ++s, jg += 128) {
    LOADJ64(B, jg + 64)
    SBAR();
    COMPJ64(A)
    LOADJ64(A, jg + 128)
    SBAR();
    COMPJ64(B)
  }
  COMPJ64(A)
#undef LOADJ64
#undef COMPJ64

  {
    const f32x4* accp[4] = {&accy0, &accy1, &accy2, &accy3};
#pragma unroll
    for (int ct = 0; ct < 4; ++ct)
#pragma unroll
      for (int r = 0; r < 4; ++r) red[w][ct * 4 + r][lane] = (*accp[ct])[r];
  }
  __syncthreads();
  if (w == 0) {
#pragma unroll
    for (int k = 0; k < 16; k += 2) {
      const float va = red[0][k][lane] + red[1][k][lane] + red[2][k][lane] +
                       red[3][k][lane];
      const float vb = red[0][k + 1][lane] + red[1][k + 1][lane] +
                       red[2][k + 1][lane] + red[3][k + 1][lane];
      const int c0 = ((k >> 2) << 4) + hi * 4 + (k & 3);
      *(uint*)&ytile[il * 72 + c0] = pkbf(va, vb);
    }
  }
  __syncthreads();

  const short8 af0 = *(const short8*)&wWb[(size_t)(w * 16 + il) * kC + hi * 8];
  const short8 af1 = *(const short8*)&wWb[(size_t)(w * 16 + il) * kC + 32 + hi * 8];
  const short8 by0 = *(const short8*)&ytile[il * 72 + hi * 8];
  const short8 by1 = *(const short8*)&ytile[il * 72 + 32 + hi * 8];
  f32x4 o4 = {0.f, 0.f, 0.f, 0.f};
  o4 = __builtin_amdgcn_mfma_f32_16x16x32_bf16(af0, by0, o4, 0, 0, 0);
  o4 = __builtin_amdgcn_mfma_f32_16x16x32_bf16(af1, by1, o4, 0, 0, 0);
  const float alpha = alphap[0];
#pragma unroll
  for (int r = 0; r < 4; ++r) {
    const int o = w * 16 + hi * 4 + r;
    const size_t idx = ((size_t)b * kC + o) * kN + i0 + il;
    const float xv = x1[idx];
    const float p = xv >= 0.f ? xv : alpha * xv;
    z[idx] = o4[r] + p + xv;
  }
}

extern "C" void kernel_launch(void* const* d_in, const int* in_sizes, int n_in,
                              void* d_out, int out_size, void* d_ws, size_t ws_size,
                              hipStream_t stream) {
  const float* x      = (const float*)d_in[0];
  const float* w1     = (const float*)d_in[1];
  const float* w2     = (const float*)d_in[2];
  const float* wg     = (const float*)d_in[3];
  const float* wth    = (const float*)d_in[4];
  const float* wph    = (const float*)d_in[5];
  const float* wWm    = (const float*)d_in[6];
  const float* alphap = (const float*)d_in[7];
  float* out = (float*)d_out;

  const size_t SZ = (size_t)kB * kC * kN;  // 819200 elements
  float* x1 = (float*)d_ws;                          // [B][C][N] f32
  float* pT = x1 + SZ;                               // [B][N][C] f32; reused as z
  __hip_bfloat16* thb = (__hip_bfloat16*)(pT + SZ);  // [B][N][C] bf16
  __hip_bfloat16* phb = thb + SZ;
  __hip_bfloat16* gb  = phb + SZ;
  __hip_bfloat16* gT  = gb + SZ;                     // [B][C][N] bf16 (rs-scaled)
  float* partial = (float*)(gT + SZ);                // [B][4][N] f32
  float* w1t = partial + (size_t)kB * 4 * kN;
  float* w2t = w1t + kC * kC * 9;
  float* wt3 = w2t + kC * kC * 9;
  __hip_bfloat16* wWb = (__hip_bfloat16*)(wt3 + 3 * kC * kC);
  float* z = pT;  // pT dead after k_pw3

  k_prep<<<144, 256, 0, stream>>>(w1, w2, wg, wth, wph, wWm, w1t, w2t,
                                  wt3, wt3 + kC * kC, wt3 + 2 * kC * kC, wWb);
  k_conv3x3<0><<<dim3(25, 4, kB), 256, 0, stream>>>(x, w1t, alphap, x1, pT);
  k_pw3<<<dim3(kN / 64, kB, 3), 64, 0, stream>>>(pT, wt3, thb);
  k_colstat<<<dim3(kN / 64, 4, kB), 256, 0, stream>>>(thb, phb, partial);
  k_gscale<<<dim3(kN / 64, kB), 256, 0, stream>>>(gb, partial, gT);
  k_nl<<<dim3(kN / 16, kB), 256, 0, stream>>>(thb, phb, gT, wWb, x1, alphap, z);
  k_conv3x3<1><<<dim3(25, 4, kB), 256, 0, stream>>>(z, w2t, alphap, out, nullptr);
}

// Round 7
// 353.124 us; speedup vs baseline: 1.2312x; 1.2289x over previous
//
#include <hip/hip_runtime.h>
#include <hip/hip_bf16.h>
#include <cstddef>

// NLBasicBlock fused, round 7: k_nl / k_colstat rebuilt on the 2-phase
// global_load_lds double-buffer template (learn_hip m230/m248). Loads have no
// dest VGPR -> compiler cannot re-serialize them; they fly during compute and
// drain at the barrier's implicit vmcnt(0). LDS is staged in fragment-linear
// order (per-lane gather on the GLOBAL side, m173) so every ds_read_b128 is
// conflict-free. Two statically-named buffers (not buf[cur]) so alias
// analysis proves stage-writes are disjoint from compute-reads.

constexpr int kB = 2, kC = 64, kH = 80, kW = 80, kN = kH * kW;
constexpr int kNT = kN / 64;  // 100 tiles of 64
constexpr float kLOG2E = 1.4426950408889634f;
constexpr float kSHIFT = 28.853900817779268f;  // 20 * log2(e)

typedef __attribute__((ext_vector_type(8))) short short8;
typedef __attribute__((ext_vector_type(4))) float f32x4;

__device__ __forceinline__ int refl(int i, int n) {
  return i < 0 ? -i : (i >= n ? 2 * n - 2 - i : i);
}

__device__ __forceinline__ uint pkbf(float a, float b) {
  union { __hip_bfloat162 h; uint u; } x;
  x.h.x = __float2bfloat16(a);
  x.h.y = __float2bfloat16(b);
  return x.u;
}

// async global->LDS, 16B per lane; dest = (wave-uniform base) + lane*16,
// source is per-lane.
#define GL16(gsrc, ldst)                                                    \
  __builtin_amdgcn_global_load_lds(                                         \
      (__attribute__((address_space(1))) void*)(char*)(gsrc),               \
      (__attribute__((address_space(3))) void*)(ldst), 16, 0, 0)

#define FMA64(wrp, xv)                                   \
  {                                                      \
    _Pragma("unroll") for (int o_ = 0; o_ < 64; ++o_)    \
        acc[o_] += (wrp)[o_] * (xv);                     \
  }

// ---- weight prep
__global__ void k_prep(const float* __restrict__ w1, const float* __restrict__ w2,
                       const float* __restrict__ wg, const float* __restrict__ wth,
                       const float* __restrict__ wph, const float* __restrict__ wWm,
                       float* __restrict__ w1t, float* __restrict__ w2t,
                       float* __restrict__ wtht, float* __restrict__ wpht,
                       float* __restrict__ wgt, __hip_bfloat16* __restrict__ wWb) {
  int idx = blockIdx.x * 256 + threadIdx.x;
  if (idx < kC * kC * 9) {
    int o = idx / (kC * 9);
    int r = idx % (kC * 9);
    int ci = r / 9, tap = r % 9;
    int d = (ci * 9 + tap) * kC + o;
    w1t[d] = w1[idx];
    w2t[d] = w2[idx];
  }
  if (idx < kC * kC) {
    int o = idx / kC, c = idx % kC;
    int d = c * kC + o;
    wtht[d] = wth[idx];
    wpht[d] = wph[idx];
    wgt[d] = wg[idx];
    wWb[idx] = __float2bfloat16(wWm[idx]);
  }
}

// ---- 3x3 reflect conv (unchanged)
template <int MODE>
__global__ __launch_bounds__(256) void k_conv3x3(
    const float* __restrict__ src, const float* __restrict__ wt,
    const float* __restrict__ alphap, float* __restrict__ dst_raw,
    float* __restrict__ dst_pt) {
  const int tile = blockIdx.x;
  const int cog = blockIdx.y;
  const int b = blockIdx.z;
  const int ty0 = (tile / 5) * 16, tx0 = (tile % 5) * 16;
  const int tid = threadIdx.x;
  const int ty = tid / 16, tx = tid % 16;
  const float alpha = alphap[0];

  __shared__ float lds[32 * 18 * 18];
  float acc[16];
#pragma unroll
  for (int o = 0; o < 16; ++o) acc[o] = 0.f;

  for (int chunk = 0; chunk < 2; ++chunk) {
    const int ci0 = chunk * 32;
    __syncthreads();
    for (int idx = tid; idx < 32 * 324; idx += 256) {
      int cc = idx / 324;
      int r = idx % 324;
      int hh = r / 18, ww = r % 18;
      int gh = refl(ty0 - 1 + hh, kH);
      int gw = refl(tx0 - 1 + ww, kW);
      lds[idx] = src[(((size_t)b * kC + ci0 + cc) * kH + gh) * kW + gw];
    }
    __syncthreads();
    for (int cc = 0; cc < 32; ++cc) {
#pragma unroll
      for (int tap = 0; tap < 9; ++tap) {
        const int dh = tap / 3, dw = tap % 3;
        const float xv = lds[cc * 324 + (ty + dh) * 18 + (tx + dw)];
        const float* wr = wt + ((size_t)(ci0 + cc) * 9 + tap) * kC + cog * 16;
#pragma unroll
        for (int o = 0; o < 16; ++o) acc[o] += wr[o] * xv;
      }
    }
  }

  const int n = (ty0 + ty) * kW + (tx0 + tx);
#pragma unroll
  for (int o = 0; o < 16; ++o) {
    const int co = cog * 16 + o;
    const float v = acc[o];
    const float p = v >= 0.f ? v : alpha * v;
    if (MODE == 0) {
      dst_raw[((size_t)b * kC + co) * kN + n] = v;
      dst_pt[((size_t)b * kN + n) * kC + co] = p;
    } else {
      dst_raw[((size_t)b * kC + co) * kN + n] = p;
    }
  }
}

// ---- three 1x1 convs -> bf16 pixel-major
__global__ __launch_bounds__(64) void k_pw3(const float* __restrict__ pT,
                                            const float* __restrict__ wt3,
                                            __hip_bfloat16* __restrict__ outb) {
  const int m = blockIdx.z, b = blockIdx.y;
  const int n = blockIdx.x * 64 + threadIdx.x;
  const float* wt = wt3 + (size_t)m * kC * kC;
  const float4* p4 = (const float4*)(pT + ((size_t)b * kN + n) * kC);
  float acc[64];
#pragma unroll
  for (int o = 0; o < 64; ++o) acc[o] = 0.f;
#pragma unroll
  for (int cq = 0; cq < 16; ++cq) {
    const float4 t = p4[cq];
    const float* wr = wt + cq * 4 * 64;
    FMA64(wr, t.x);
    FMA64(wr + 64, t.y);
    FMA64(wr + 128, t.z);
    FMA64(wr + 192, t.w);
  }
  uint* d32 = (uint*)(outb + (((size_t)m * kB + b) * kN + n) * kC);
#pragma unroll
  for (int q = 0; q < 32; ++q) d32[q] = pkbf(acc[2 * q], acc[2 * q + 1]);
}

// ---- column sums -> rs[b][j] = 1/sum_i exp(theta_i.phi_j - 20).
// Block = 32 j (2 waves x 16 j). Loop over all i in 64-row tiles staged to
// LDS via global_load_lds in B-fragment-linear order.
__global__ __launch_bounds__(128) void k_colstat(
    const __hip_bfloat16* __restrict__ th, const __hip_bfloat16* __restrict__ ph,
    float* __restrict__ rs) {
  const int b = blockIdx.y;
  const int lane = threadIdx.x & 63, w = threadIdx.x >> 6;
  const int il = lane & 15, hi = lane >> 4;
  const int j0w = blockIdx.x * 32 + w * 16;

  __shared__ __align__(16) ushort tbufA[4096], tbufB[4096];  // 8KB each

  const __hip_bfloat16* thB = th + (size_t)b * kN * kC;
  const short8 af0 = *(const short8*)&ph[((size_t)b * kN + j0w + il) * kC + hi * 8];
  const short8 af1 = *(const short8*)&ph[((size_t)b * kN + j0w + il) * kC + 32 + hi * 8];

  // theta fragment f (0..7): row i = (f>>1)*16 + il, col = (f&1)*32 + hi*8.
  // Wave w stages f = 4w .. 4w+3.
  const int f0 = 4 * w;
  const char* st[4];
#pragma unroll
  for (int k = 0; k < 4; ++k) {
    const int f = f0 + k;
    st[k] = (const char*)&thB[(size_t)((f >> 1) * 16 + il) * kC + (f & 1) * 32 + hi * 8];
  }

#define CSTAGE(DST)                                                         \
  {                                                                         \
    _Pragma("unroll") for (int k = 0; k < 4; ++k) {                         \
      GL16(st[k], &DST[(f0 + k) * 512]);                                    \
      st[k] += (size_t)64 * kC * 2;                                         \
    }                                                                       \
  }

#define CCOMP(SRC)                                                          \
  {                                                                         \
    const ushort* bp_ = SRC;                                                \
    _Pragma("unroll") for (int s = 0; s < 4; ++s) {                         \
      const short8 b0 = *(const short8*)&bp_[(2 * s) * 512 + lane * 8];     \
      const short8 b1 = *(const short8*)&bp_[(2 * s + 1) * 512 + lane * 8]; \
      f32x4 sa = {0.f, 0.f, 0.f, 0.f};                                      \
      sa = __builtin_amdgcn_mfma_f32_16x16x32_bf16(af0, b0, sa, 0, 0, 0);   \
      sa = __builtin_amdgcn_mfma_f32_16x16x32_bf16(af1, b1, sa, 0, 0, 0);   \
      _Pragma("unroll") for (int r = 0; r < 4; ++r)                         \
          cs[r] += exp2f(fmaf(sa[r], kLOG2E, -kSHIFT));                     \
    }                                                                       \
  }

  float cs[4] = {0.f, 0.f, 0.f, 0.f};
  CSTAGE(tbufA);
  __syncthreads();
#pragma unroll 1
  for (int t = 0; t < kNT / 2; ++t) {
    CSTAGE(tbufB);
    CCOMP(tbufA);
    __syncthreads();
    CSTAGE(tbufA);   // last pass over-stages into safe ws region
    CCOMP(tbufB);
    __syncthreads();
  }
#undef CSTAGE
#undef CCOMP

#pragma unroll
  for (int r = 0; r < 4; ++r) {
    cs[r] += __shfl_xor(cs[r], 1);
    cs[r] += __shfl_xor(cs[r], 2);
    cs[r] += __shfl_xor(cs[r], 4);
    cs[r] += __shfl_xor(cs[r], 8);
  }
  if (il == 0) {
#pragma unroll
    for (int r = 0; r < 4; ++r)
      rs[(size_t)b * kN + j0w + hi * 4 + r] = 1.0f / cs[r];
  }
}

// ---- gT[b][c][j] = bf16( g[b][j][c] * rs[b][j] )
__global__ __launch_bounds__(256) void k_gscale(
    const __hip_bfloat16* __restrict__ gb, const float* __restrict__ rs,
    __hip_bfloat16* __restrict__ gT) {
  const int b = blockIdx.y;
  const int j0 = blockIdx.x * 64;
  const int t = threadIdx.x;
  __shared__ ushort tile[64][66];
  __shared__ float rsv[64];
  if (t < 64) rsv[t] = rs[(size_t)b * kN + j0 + t];
  {
    const int jl = t >> 2, cseg = (t & 3) * 16;
    const ushort* src = (const ushort*)&gb[((size_t)b * kN + j0 + jl) * kC + cseg];
    union { short8 v; ushort u[8]; } u0, u1;
    u0.v = *(const short8*)src;
    u1.v = *(const short8*)(src + 8);
#pragma unroll
    for (int k = 0; k < 8; ++k) {
      tile[jl][cseg + k] = u0.u[k];
      tile[jl][cseg + 8 + k] = u1.u[k];
    }
  }
  __syncthreads();
  const int c = t >> 2, jseg = (t & 3) * 16;
  union { short8 v; ushort u[8]; } o0, o1;
#pragma unroll
  for (int k = 0; k < 16; ++k) {
    const int j = jseg + k;
    const float gv = __uint_as_float((uint)tile[j][c] << 16);
    union { __hip_bfloat16 h; ushort us; } cv;
    cv.h = __float2bfloat16(gv * rsv[j]);
    if (k < 8) o0.u[k] = cv.us; else o1.u[k - 8] = cv.us;
  }
  short8* dst = (short8*)&gT[((size_t)b * kC + c) * kN + j0 + jseg];
  dst[0] = o0.v;
  dst[1] = o1.v;
}

// ---- fused pass B + W_y + residuals.
// Block = 32 i (2 waves x 16 i); loops over ALL j in 64-tiles. Per tile the
// block stages phi (8KB) + gT (8KB) into LDS in fragment-linear order (the
// sigma permutation is baked into the per-lane GLOBAL source addresses), so
// ds_read_b128 fragments are linear and conflict-free. No cross-wave reduce:
// each wave owns its 16-i output fully, including the fused W_y.
__global__ __launch_bounds__(128) void k_nl(
    const __hip_bfloat16* __restrict__ th, const __hip_bfloat16* __restrict__ ph,
    const __hip_bfloat16* __restrict__ gT, const __hip_bfloat16* __restrict__ wWb,
    const float* __restrict__ x1, const float* __restrict__ alphap,
    float* __restrict__ z) {
  const int b = blockIdx.y;
  const int lane = threadIdx.x & 63, w = threadIdx.x >> 6;
  const int il = lane & 15, hi = lane >> 4;
  const int iw = blockIdx.x * 32 + w * 16;
  const int jbase = ((il >> 2) << 3) + (il & 3);  // sigma(row=il)

  __shared__ __align__(16) ushort bufA[8192], bufB[8192];  // [phi 8KB|gT 8KB]
  __shared__ __align__(16) ushort yt2[2][16 * 72];

  const __hip_bfloat16* phB = ph + (size_t)b * kN * kC;
  const __hip_bfloat16* gTB = gT + (size_t)b * kC * kN;

  const short8 tb0 = *(const short8*)&th[((size_t)b * kN + iw + il) * kC + hi * 8];
  const short8 tb1 = *(const short8*)&th[((size_t)b * kN + iw + il) * kC + 32 + hi * 8];

  // phi frag f: row = jbase + ((f>>1)&1)*4 + ((f>>2)&1)*32, col = (f&1)*32+hi*8
  // gT  frag f: row c = (f&3)*16 + il, col j = ((f>>2)&1)*32 + hi*8
  // Wave w stages f = 4w..4w+3 of each.
  const int f0 = 4 * w;
  const char* sp[4];
  const char* sg[4];
#pragma unroll
  for (int k = 0; k < 4; ++k) {
    const int f = f0 + k;
    const int pr = jbase + ((f >> 1) & 1) * 4 + ((f >> 2) & 1) * 32;
    const int pc = (f & 1) * 32 + hi * 8;
    sp[k] = (const char*)&phB[(size_t)pr * kC + pc];
    const int gc = (f & 3) * 16 + il;
    const int gj = ((f >> 2) & 1) * 32 + hi * 8;
    sg[k] = (const char*)&gTB[(size_t)gc * kN + gj];
  }

#define NLSTAGE(DST)                                                        \
  {                                                                         \
    _Pragma("unroll") for (int k = 0; k < 4; ++k) {                         \
      GL16(sp[k], &DST[(f0 + k) * 512]);                                    \
      GL16(sg[k], &DST[4096 + (f0 + k) * 512]);                             \
      sp[k] += (size_t)64 * kC * 2;                                         \
      sg[k] += (size_t)64 * 2;                                              \
    }                                                                       \
  }

#define NLCOMP(SRC)                                                           \
  {                                                                           \
    const ushort* bp_ = SRC;                                                  \
    const short8 pa0 = *(const short8*)&bp_[0 * 512 + lane * 8];              \
    const short8 pa1 = *(const short8*)&bp_[1 * 512 + lane * 8];              \
    const short8 pa2 = *(const short8*)&bp_[2 * 512 + lane * 8];              \
    const short8 pa3 = *(const short8*)&bp_[3 * 512 + lane * 8];              \
    const short8 pa4 = *(const short8*)&bp_[4 * 512 + lane * 8];              \
    const short8 pa5 = *(const short8*)&bp_[5 * 512 + lane * 8];              \
    const short8 pa6 = *(const short8*)&bp_[6 * 512 + lane * 8];              \
    const short8 pa7 = *(const short8*)&bp_[7 * 512 + lane * 8];              \
    const short8 ga0 = *(const short8*)&bp_[4096 + 0 * 512 + lane * 8];       \
    const short8 ga1 = *(const short8*)&bp_[4096 + 1 * 512 + lane * 8];       \
    const short8 ga2 = *(const short8*)&bp_[4096 + 2 * 512 + lane * 8];       \
    const short8 ga3 = *(const short8*)&bp_[4096 + 3 * 512 + lane * 8];       \
    const short8 ga4 = *(const short8*)&bp_[4096 + 4 * 512 + lane * 8];       \
    const short8 ga5 = *(const short8*)&bp_[4096 + 5 * 512 + lane * 8];       \
    const short8 ga6 = *(const short8*)&bp_[4096 + 6 * 512 + lane * 8];       \
    const short8 ga7 = *(const short8*)&bp_[4096 + 7 * 512 + lane * 8];       \
    f32x4 s0 = {0.f, 0.f, 0.f, 0.f};                                          \
    f32x4 s1 = {0.f, 0.f, 0.f, 0.f};                                          \
    f32x4 s2 = {0.f, 0.f, 0.f, 0.f};                                          \
    f32x4 s3 = {0.f, 0.f, 0.f, 0.f};                                          \
    s0 = __builtin_amdgcn_mfma_f32_16x16x32_bf16(pa0, tb0, s0, 0, 0, 0);      \
    s0 = __builtin_amdgcn_mfma_f32_16x16x32_bf16(pa1, tb1, s0, 0, 0, 0);      \
    s1 = __builtin_amdgcn_mfma_f32_16x16x32_bf16(pa2, tb0, s1, 0, 0, 0);      \
    s1 = __builtin_amdgcn_mfma_f32_16x16x32_bf16(pa3, tb1, s1, 0, 0, 0);      \
    s2 = __builtin_amdgcn_mfma_f32_16x16x32_bf16(pa4, tb0, s2, 0, 0, 0);      \
    s2 = __builtin_amdgcn_mfma_f32_16x16x32_bf16(pa5, tb1, s2, 0, 0, 0);      \
    s3 = __builtin_amdgcn_mfma_f32_16x16x32_bf16(pa6, tb0, s3, 0, 0, 0);      \
    s3 = __builtin_amdgcn_mfma_f32_16x16x32_bf16(pa7, tb1, s3, 0, 0, 0);      \
    short8 pb0, pb1;                                                          \
    {                                                                         \
      uint* pw_ = (uint*)&pb0;                                                \
      pw_[0] = pkbf(exp2f(fmaf(s0[0], kLOG2E, -kSHIFT)),                      \
                    exp2f(fmaf(s0[1], kLOG2E, -kSHIFT)));                     \
      pw_[1] = pkbf(exp2f(fmaf(s0[2], kLOG2E, -kSHIFT)),                      \
                    exp2f(fmaf(s0[3], kLOG2E, -kSHIFT)));                     \
      pw_[2] = pkbf(exp2f(fmaf(s1[0], kLOG2E, -kSHIFT)),                      \
                    exp2f(fmaf(s1[1], kLOG2E, -kSHIFT)));                     \
      pw_[3] = pkbf(exp2f(fmaf(s1[2], kLOG2E, -kSHIFT)),                      \
                    exp2f(fmaf(s1[3], kLOG2E, -kSHIFT)));                     \
    }                                                                         \
    accy0 = __builtin_amdgcn_mfma_f32_16x16x32_bf16(ga0, pb0, accy0, 0, 0, 0);\
    accy1 = __builtin_amdgcn_mfma_f32_16x16x32_bf16(ga1, pb0, accy1, 0, 0, 0);\
    {                                                                         \
      uint* pw_ = (uint*)&pb1;                                                \
      pw_[0] = pkbf(exp2f(fmaf(s2[0], kLOG2E, -kSHIFT)),                      \
                    exp2f(fmaf(s2[1], kLOG2E, -kSHIFT)));                     \
      pw_[1] = pkbf(exp2f(fmaf(s2[2], kLOG2E, -kSHIFT)),                      \
                    exp2f(fmaf(s2[3], kLOG2E, -kSHIFT)));                     \
      pw_[2] = pkbf(exp2f(fmaf(s3[0], kLOG2E, -kSHIFT)),                      \
                    exp2f(fmaf(s3[1], kLOG2E, -kSHIFT)));                     \
      pw_[3] = pkbf(exp2f(fmaf(s3[2], kLOG2E, -kSHIFT)),                      \
                    exp2f(fmaf(s3[3], kLOG2E, -kSHIFT)));                     \
    }                                                                         \
    accy2 = __builtin_amdgcn_mfma_f32_16x16x32_bf16(ga2, pb0, accy2, 0, 0, 0);\
    accy3 = __builtin_amdgcn_mfma_f32_16x16x32_bf16(ga3, pb0, accy3, 0, 0, 0);\
    accy0 = __builtin_amdgcn_mfma_f32_16x16x32_bf16(ga4, pb1, accy0, 0, 0, 0);\
    accy1 = __builtin_amdgcn_mfma_f32_16x16x32_bf16(ga5, pb1, accy1, 0, 0, 0);\
    accy2 = __builtin_amdgcn_mfma_f32_16x16x32_bf16(ga6, pb1, accy2, 0, 0, 0);\
    accy3 = __builtin_amdgcn_mfma_f32_16x16x32_bf16(ga7, pb1, accy3, 0, 0, 0);\
  }

  f32x4 accy0 = {0.f, 0.f, 0.f, 0.f};
  f32x4 accy1 = {0.f, 0.f, 0.f, 0.f};
  f32x4 accy2 = {0.f, 0.f, 0.f, 0.f};
  f32x4 accy3 = {0.f, 0.f, 0.f, 0.f};

  NLSTAGE(bufA);
  __syncthreads();
#pragma unroll 1
  for (int t = 0; t < kNT / 2; ++t) {
    NLSTAGE(bufB);
    NLCOMP(bufA);
    __syncthreads();
    NLSTAGE(bufA);   // last pass over-stages into safe ws region
    NLCOMP(bufB);
    __syncthreads();
  }
#undef NLSTAGE
#undef NLCOMP

  // y (bf16) through per-wave LDS tile to re-fragment for W_y
  ushort* yt = yt2[w];
  *(uint*)&yt[il * 72 + 0 + hi * 4 + 0]  = pkbf(accy0[0], accy0[1]);
  *(uint*)&yt[il * 72 + 0 + hi * 4 + 2]  = pkbf(accy0[2], accy0[3]);
  *(uint*)&yt[il * 72 + 16 + hi * 4 + 0] = pkbf(accy1[0], accy1[1]);
  *(uint*)&yt[il * 72 + 16 + hi * 4 + 2] = pkbf(accy1[2], accy1[3]);
  *(uint*)&yt[il * 72 + 32 + hi * 4 + 0] = pkbf(accy2[0], accy2[1]);
  *(uint*)&yt[il * 72 + 32 + hi * 4 + 2] = pkbf(accy2[2], accy2[3]);
  *(uint*)&yt[il * 72 + 48 + hi * 4 + 0] = pkbf(accy3[0], accy3[1]);
  *(uint*)&yt[il * 72 + 48 + hi * 4 + 2] = pkbf(accy3[2], accy3[3]);

  const short8 by0 = *(const short8*)&yt[il * 72 + hi * 8];
  const short8 by1 = *(const short8*)&yt[il * 72 + 32 + hi * 8];
  const float alpha = alphap[0];
#pragma unroll
  for (int q = 0; q < 4; ++q) {
    const short8 af0 = *(const short8*)&wWb[(size_t)(q * 16 + il) * kC + hi * 8];
    const short8 af1 = *(const short8*)&wWb[(size_t)(q * 16 + il) * kC + 32 + hi * 8];
    f32x4 o4 = {0.f, 0.f, 0.f, 0.f};
    o4 = __builtin_amdgcn_mfma_f32_16x16x32_bf16(af0, by0, o4, 0, 0, 0);
    o4 = __builtin_amdgcn_mfma_f32_16x16x32_bf16(af1, by1, o4, 0, 0, 0);
#pragma unroll
    for (int r = 0; r < 4; ++r) {
      const int o = q * 16 + hi * 4 + r;
      const size_t idx = ((size_t)b * kC + o) * kN + iw + il;
      const float xv = x1[idx];
      const float p = xv >= 0.f ? xv : alpha * xv;
      z[idx] = o4[r] + p + xv;
    }
  }
}

extern "C" void kernel_launch(void* const* d_in, const int* in_sizes, int n_in,
                              void* d_out, int out_size, void* d_ws, size_t ws_size,
                              hipStream_t stream) {
  const float* x      = (const float*)d_in[0];
  const float* w1     = (const float*)d_in[1];
  const float* w2     = (const float*)d_in[2];
  const float* wg     = (const float*)d_in[3];
  const float* wth    = (const float*)d_in[4];
  const float* wph    = (const float*)d_in[5];
  const float* wWm    = (const float*)d_in[6];
  const float* alphap = (const float*)d_in[7];
  float* out = (float*)d_out;

  const size_t SZ = (size_t)kB * kC * kN;  // 819200 elements
  float* x1 = (float*)d_ws;                          // [B][C][N] f32
  float* pT = x1 + SZ;                               // [B][N][C] f32; reused as z
  __hip_bfloat16* thb = (__hip_bfloat16*)(pT + SZ);  // [B][N][C] bf16
  __hip_bfloat16* phb = thb + SZ;
  __hip_bfloat16* gb  = phb + SZ;
  __hip_bfloat16* gT  = gb + SZ;                     // [B][C][N] bf16 (rs-scaled)
  float* rs = (float*)(gT + SZ);                     // [B][N] f32 (1/colsum)
  float* w1t = rs + (size_t)kB * kN;
  float* w2t = w1t + kC * kC * 9;
  float* wt3 = w2t + kC * kC * 9;
  __hip_bfloat16* wWb = (__hip_bfloat16*)(wt3 + 3 * kC * kC);
  float* z = pT;  // pT dead after k_pw3

  k_prep<<<144, 256, 0, stream>>>(w1, w2, wg, wth, wph, wWm, w1t, w2t,
                                  wt3, wt3 + kC * kC, wt3 + 2 * kC * kC, wWb);
  k_conv3x3<0><<<dim3(25, 4, kB), 256, 0, stream>>>(x, w1t, alphap, x1, pT);
  k_pw3<<<dim3(kN / 64, kB, 3), 64, 0, stream>>>(pT, wt3, thb);
  k_colstat<<<dim3(kN / 32, kB), 128, 0, stream>>>(thb, phb, rs);
  k_gscale<<<dim3(kN / 64, kB), 256, 0, stream>>>(gb, rs, gT);
  k_nl<<<dim3(kN / 32, kB), 128, 0, stream>>>(thb, phb, gT, wWb, x1, alphap, z);
  k_conv3x3<1><<<dim3(25, 4, kB), 256, 0, stream>>>(z, w2t, alphap, out, nullptr);
}

// Round 8
// 302.936 us; speedup vs baseline: 1.4352x; 1.1657x over previous
//
#include <hip/hip_runtime.h>
#include <hip/hip_bf16.h>
#include <cstddef>

// NLBasicBlock fused, round 8: split-K over j (4 chunks) for occupancy.
// R7's k_nl was correct but grid=400 blocks -> 1.56 blocks/CU -> every
// barrier drain idled the CU (Occupancy 7.7%). Now k_nl grid=1600 (5
// blocks/CU at 32KB LDS); partial y written as bf16 in register-linear
// layout; k_wy sums 4 partials + fused W_y + residuals (R7's verified
// epilogue). k_colstat gets its i-split back (partials summed in gscale).

constexpr int kB = 2, kC = 64, kH = 80, kW = 80, kN = kH * kW;
constexpr float kLOG2E = 1.4426950408889634f;
constexpr float kSHIFT = 28.853900817779268f;  // 20 * log2(e)

typedef __attribute__((ext_vector_type(8))) short short8;
typedef __attribute__((ext_vector_type(4))) float f32x4;

__device__ __forceinline__ int refl(int i, int n) {
  return i < 0 ? -i : (i >= n ? 2 * n - 2 - i : i);
}

__device__ __forceinline__ uint pkbf(float a, float b) {
  union { __hip_bfloat162 h; uint u; } x;
  x.h.x = __float2bfloat16(a);
  x.h.y = __float2bfloat16(b);
  return x.u;
}

#define GL16(gsrc, ldst)                                                    \
  __builtin_amdgcn_global_load_lds(                                         \
      (__attribute__((address_space(1))) void*)(char*)(gsrc),               \
      (__attribute__((address_space(3))) void*)(ldst), 16, 0, 0)

#define FMA64(wrp, xv)                                   \
  {                                                      \
    _Pragma("unroll") for (int o_ = 0; o_ < 64; ++o_)    \
        acc[o_] += (wrp)[o_] * (xv);                     \
  }

// ---- weight prep
__global__ void k_prep(const float* __restrict__ w1, const float* __restrict__ w2,
                       const float* __restrict__ wg, const float* __restrict__ wth,
                       const float* __restrict__ wph, const float* __restrict__ wWm,
                       float* __restrict__ w1t, float* __restrict__ w2t,
                       float* __restrict__ wtht, float* __restrict__ wpht,
                       float* __restrict__ wgt, __hip_bfloat16* __restrict__ wWb) {
  int idx = blockIdx.x * 256 + threadIdx.x;
  if (idx < kC * kC * 9) {
    int o = idx / (kC * 9);
    int r = idx % (kC * 9);
    int ci = r / 9, tap = r % 9;
    int d = (ci * 9 + tap) * kC + o;
    w1t[d] = w1[idx];
    w2t[d] = w2[idx];
  }
  if (idx < kC * kC) {
    int o = idx / kC, c = idx % kC;
    int d = c * kC + o;
    wtht[d] = wth[idx];
    wpht[d] = wph[idx];
    wgt[d] = wg[idx];
    wWb[idx] = __float2bfloat16(wWm[idx]);
  }
}

// ---- 3x3 reflect conv (unchanged)
template <int MODE>
__global__ __launch_bounds__(256) void k_conv3x3(
    const float* __restrict__ src, const float* __restrict__ wt,
    const float* __restrict__ alphap, float* __restrict__ dst_raw,
    float* __restrict__ dst_pt) {
  const int tile = blockIdx.x;
  const int cog = blockIdx.y;
  const int b = blockIdx.z;
  const int ty0 = (tile / 5) * 16, tx0 = (tile % 5) * 16;
  const int tid = threadIdx.x;
  const int ty = tid / 16, tx = tid % 16;
  const float alpha = alphap[0];

  __shared__ float lds[32 * 18 * 18];
  float acc[16];
#pragma unroll
  for (int o = 0; o < 16; ++o) acc[o] = 0.f;

  for (int chunk = 0; chunk < 2; ++chunk) {
    const int ci0 = chunk * 32;
    __syncthreads();
    for (int idx = tid; idx < 32 * 324; idx += 256) {
      int cc = idx / 324;
      int r = idx % 324;
      int hh = r / 18, ww = r % 18;
      int gh = refl(ty0 - 1 + hh, kH);
      int gw = refl(tx0 - 1 + ww, kW);
      lds[idx] = src[(((size_t)b * kC + ci0 + cc) * kH + gh) * kW + gw];
    }
    __syncthreads();
    for (int cc = 0; cc < 32; ++cc) {
#pragma unroll
      for (int tap = 0; tap < 9; ++tap) {
        const int dh = tap / 3, dw = tap % 3;
        const float xv = lds[cc * 324 + (ty + dh) * 18 + (tx + dw)];
        const float* wr = wt + ((size_t)(ci0 + cc) * 9 + tap) * kC + cog * 16;
#pragma unroll
        for (int o = 0; o < 16; ++o) acc[o] += wr[o] * xv;
      }
    }
  }

  const int n = (ty0 + ty) * kW + (tx0 + tx);
#pragma unroll
  for (int o = 0; o < 16; ++o) {
    const int co = cog * 16 + o;
    const float v = acc[o];
    const float p = v >= 0.f ? v : alpha * v;
    if (MODE == 0) {
      dst_raw[((size_t)b * kC + co) * kN + n] = v;
      dst_pt[((size_t)b * kN + n) * kC + co] = p;
    } else {
      dst_raw[((size_t)b * kC + co) * kN + n] = p;
    }
  }
}

// ---- three 1x1 convs -> bf16 pixel-major
__global__ __launch_bounds__(64) void k_pw3(const float* __restrict__ pT,
                                            const float* __restrict__ wt3,
                                            __hip_bfloat16* __restrict__ outb) {
  const int m = blockIdx.z, b = blockIdx.y;
  const int n = blockIdx.x * 64 + threadIdx.x;
  const float* wt = wt3 + (size_t)m * kC * kC;
  const float4* p4 = (const float4*)(pT + ((size_t)b * kN + n) * kC);
  float acc[64];
#pragma unroll
  for (int o = 0; o < 64; ++o) acc[o] = 0.f;
#pragma unroll
  for (int cq = 0; cq < 16; ++cq) {
    const float4 t = p4[cq];
    const float* wr = wt + cq * 4 * 64;
    FMA64(wr, t.x);
    FMA64(wr + 64, t.y);
    FMA64(wr + 128, t.z);
    FMA64(wr + 192, t.w);
  }
  uint* d32 = (uint*)(outb + (((size_t)m * kB + b) * kN + n) * kC);
#pragma unroll
  for (int q = 0; q < 32; ++q) d32[q] = pkbf(acc[2 * q], acc[2 * q + 1]);
}

// ---- column sums (i-split 4): partial[b][ic][j] = sum_{i in chunk} exp(.)
__global__ __launch_bounds__(128) void k_colstat(
    const __hip_bfloat16* __restrict__ th, const __hip_bfloat16* __restrict__ ph,
    float* __restrict__ partial) {
  const int b = blockIdx.z, ic = blockIdx.y;
  const int lane = threadIdx.x & 63, w = threadIdx.x >> 6;
  const int il = lane & 15, hi = lane >> 4;
  const int j0w = blockIdx.x * 32 + w * 16;

  __shared__ __align__(16) ushort tbufA[4096], tbufB[4096];  // 8KB each

  const __hip_bfloat16* thB = th + (size_t)b * kN * kC;
  const short8 af0 = *(const short8*)&ph[((size_t)b * kN + j0w + il) * kC + hi * 8];
  const short8 af1 = *(const short8*)&ph[((size_t)b * kN + j0w + il) * kC + 32 + hi * 8];

  const int f0 = 4 * w;
  const char* st[4];
#pragma unroll
  for (int k = 0; k < 4; ++k) {
    const int f = f0 + k;
    st[k] = (const char*)&thB[(size_t)(ic * (kN / 4) + (f >> 1) * 16 + il) * kC +
                              (f & 1) * 32 + hi * 8];
  }

#define CSTAGE(DST)                                                         \
  {                                                                         \
    _Pragma("unroll") for (int k = 0; k < 4; ++k) {                         \
      GL16(st[k], &DST[(f0 + k) * 512]);                                    \
      st[k] += (size_t)64 * kC * 2;                                         \
    }                                                                       \
  }

#define CCOMP(SRC)                                                         \
  {                                                                        \
    const ushort* bp_ = SRC;                                               \
    _Pragma("unroll") for (int s = 0; s < 4; ++s) {                        \
      const short8 b0 = *(const short8*)&bp_[(2 * s) * 512 + lane * 8];    \
      const short8 b1 = *(const short8*)&bp_[(2 * s + 1) * 512 + lane * 8];\
      f32x4 sa = {0.f, 0.f, 0.f, 0.f};                                     \
      sa = __builtin_amdgcn_mfma_f32_16x16x32_bf16(af0, b0, sa, 0, 0, 0);  \
      sa = __builtin_amdgcn_mfma_f32_16x16x32_bf16(af1, b1, sa, 0, 0, 0);  \
      _Pragma("unroll") for (int r = 0; r < 4; ++r)                        \
          cs[r] += exp2f(fmaf(sa[r], kLOG2E, -kSHIFT));                    \
    }                                                                      \
  }

  float cs[4] = {0.f, 0.f, 0.f, 0.f};
  CSTAGE(tbufA);
  __syncthreads();
#pragma unroll 1
  for (int t = 0; t < 12; ++t) {  // 25 tiles of 64 i
    CSTAGE(tbufB);
    CCOMP(tbufA);
    __syncthreads();
    CSTAGE(tbufA);
    CCOMP(tbufB);
    __syncthreads();
  }
  CCOMP(tbufA);
#undef CSTAGE
#undef CCOMP

#pragma unroll
  for (int r = 0; r < 4; ++r) {
    cs[r] += __shfl_xor(cs[r], 1);
    cs[r] += __shfl_xor(cs[r], 2);
    cs[r] += __shfl_xor(cs[r], 4);
    cs[r] += __shfl_xor(cs[r], 8);
  }
  if (il == 0) {
    float* p = partial + (size_t)(b * 4 + ic) * kN + j0w + hi * 4;
#pragma unroll
    for (int r = 0; r < 4; ++r) p[r] = cs[r];
  }
}

// ---- gT[b][c][j] = bf16( g[b][j][c] * 1/colsum[b][j] )
__global__ __launch_bounds__(256) void k_gscale(
    const __hip_bfloat16* __restrict__ gb, const float* __restrict__ partial,
    __hip_bfloat16* __restrict__ gT) {
  const int b = blockIdx.y;
  const int j0 = blockIdx.x * 64;
  const int t = threadIdx.x;
  __shared__ ushort tile[64][66];
  __shared__ float rsv[64];
  if (t < 64) {
    const int j = j0 + t;
    float cs = partial[(size_t)(b * 4 + 0) * kN + j] +
               partial[(size_t)(b * 4 + 1) * kN + j] +
               partial[(size_t)(b * 4 + 2) * kN + j] +
               partial[(size_t)(b * 4 + 3) * kN + j];
    rsv[t] = 1.0f / cs;
  }
  {
    const int jl = t >> 2, cseg = (t & 3) * 16;
    const ushort* src = (const ushort*)&gb[((size_t)b * kN + j0 + jl) * kC + cseg];
    union { short8 v; ushort u[8]; } u0, u1;
    u0.v = *(const short8*)src;
    u1.v = *(const short8*)(src + 8);
#pragma unroll
    for (int k = 0; k < 8; ++k) {
      tile[jl][cseg + k] = u0.u[k];
      tile[jl][cseg + 8 + k] = u1.u[k];
    }
  }
  __syncthreads();
  const int c = t >> 2, jseg = (t & 3) * 16;
  union { short8 v; ushort u[8]; } o0, o1;
#pragma unroll
  for (int k = 0; k < 16; ++k) {
    const int j = jseg + k;
    const float gv = __uint_as_float((uint)tile[j][c] << 16);
    union { __hip_bfloat16 h; ushort us; } cv;
    cv.h = __float2bfloat16(gv * rsv[j]);
    if (k < 8) o0.u[k] = cv.us; else o1.u[k - 8] = cv.us;
  }
  short8* dst = (short8*)&gT[((size_t)b * kC + c) * kN + j0 + jseg];
  dst[0] = o0.v;
  dst[1] = o1.v;
}

// ---- pass B, j-split 4: partial y (bf16) per (js,b,itile), reg-linear.
__global__ __launch_bounds__(128) void k_nl(
    const __hip_bfloat16* __restrict__ th, const __hip_bfloat16* __restrict__ ph,
    const __hip_bfloat16* __restrict__ gT,
    ushort* __restrict__ py01, ushort* __restrict__ py23) {
  const int js = blockIdx.y, b = blockIdx.z;
  const int lane = threadIdx.x & 63, w = threadIdx.x >> 6;
  const int il = lane & 15, hi = lane >> 4;
  const int itile = blockIdx.x * 2 + w;
  const int iw = itile * 16;
  const int jstart = js * (kN / 4);
  const int jbase = ((il >> 2) << 3) + (il & 3);  // sigma(row=il)

  __shared__ __align__(16) ushort bufA[8192], bufB[8192];  // [phi 8KB|gT 8KB]

  const __hip_bfloat16* phB = ph + (size_t)b * kN * kC;
  const __hip_bfloat16* gTB = gT + (size_t)b * kC * kN;

  const short8 tb0 = *(const short8*)&th[((size_t)b * kN + iw + il) * kC + hi * 8];
  const short8 tb1 = *(const short8*)&th[((size_t)b * kN + iw + il) * kC + 32 + hi * 8];

  const int f0 = 4 * w;
  const char* sp[4];
  const char* sg[4];
#pragma unroll
  for (int k = 0; k < 4; ++k) {
    const int f = f0 + k;
    const int pr = jstart + jbase + ((f >> 1) & 1) * 4 + ((f >> 2) & 1) * 32;
    const int pc = (f & 1) * 32 + hi * 8;
    sp[k] = (const char*)&phB[(size_t)pr * kC + pc];
    const int gc = (f & 3) * 16 + il;
    const int gj = jstart + ((f >> 2) & 1) * 32 + hi * 8;
    sg[k] = (const char*)&gTB[(size_t)gc * kN + gj];
  }

#define NLSTAGE(DST)                                                        \
  {                                                                         \
    _Pragma("unroll") for (int k = 0; k < 4; ++k) {                         \
      GL16(sp[k], &DST[(f0 + k) * 512]);                                    \
      GL16(sg[k], &DST[4096 + (f0 + k) * 512]);                             \
      sp[k] += (size_t)64 * kC * 2;                                         \
      sg[k] += (size_t)64 * 2;                                              \
    }                                                                       \
  }

#define NLCOMP(SRC)                                                          \
  {                                                                          \
    const ushort* bp_ = SRC;                                                 \
    const short8 pa0 = *(const short8*)&bp_[0 * 512 + lane * 8];             \
    const short8 pa1 = *(const short8*)&bp_[1 * 512 + lane * 8];             \
    const short8 pa2 = *(const short8*)&bp_[2 * 512 + lane * 8];             \
    const short8 pa3 = *(const short8*)&bp_[3 * 512 + lane * 8];             \
    const short8 pa4 = *(const short8*)&bp_[4 * 512 + lane * 8];             \
    const short8 pa5 = *(const short8*)&bp_[5 * 512 + lane * 8];             \
    const short8 pa6 = *(const short8*)&bp_[6 * 512 + lane * 8];             \
    const short8 pa7 = *(const short8*)&bp_[7 * 512 + lane * 8];             \
    const short8 ga0 = *(const short8*)&bp_[4096 + 0 * 512 + lane * 8];      \
    const short8 ga1 = *(const short8*)&bp_[4096 + 1 * 512 + lane * 8];      \
    const short8 ga2 = *(const short8*)&bp_[4096 + 2 * 512 + lane * 8];      \
    const short8 ga3 = *(const short8*)&bp_[4096 + 3 * 512 + lane * 8];      \
    const short8 ga4 = *(const short8*)&bp_[4096 + 4 * 512 + lane * 8];      \
    const short8 ga5 = *(const short8*)&bp_[4096 + 5 * 512 + lane * 8];      \
    const short8 ga6 = *(const short8*)&bp_[4096 + 6 * 512 + lane * 8];      \
    const short8 ga7 = *(const short8*)&bp_[4096 + 7 * 512 + lane * 8];      \
    f32x4 s0 = {0.f, 0.f, 0.f, 0.f};                                         \
    f32x4 s1 = {0.f, 0.f, 0.f, 0.f};                                         \
    f32x4 s2 = {0.f, 0.f, 0.f, 0.f};                                         \
    f32x4 s3 = {0.f, 0.f, 0.f, 0.f};                                         \
    s0 = __builtin_amdgcn_mfma_f32_16x16x32_bf16(pa0, tb0, s0, 0, 0, 0);     \
    s0 = __builtin_amdgcn_mfma_f32_16x16x32_bf16(pa1, tb1, s0, 0, 0, 0);     \
    s1 = __builtin_amdgcn_mfma_f32_16x16x32_bf16(pa2, tb0, s1, 0, 0, 0);     \
    s1 = __builtin_amdgcn_mfma_f32_16x16x32_bf16(pa3, tb1, s1, 0, 0, 0);     \
    s2 = __builtin_amdgcn_mfma_f32_16x16x32_bf16(pa4, tb0, s2, 0, 0, 0);     \
    s2 = __builtin_amdgcn_mfma_f32_16x16x32_bf16(pa5, tb1, s2, 0, 0, 0);     \
    s3 = __builtin_amdgcn_mfma_f32_16x16x32_bf16(pa6, tb0, s3, 0, 0, 0);     \
    s3 = __builtin_amdgcn_mfma_f32_16x16x32_bf16(pa7, tb1, s3, 0, 0, 0);     \
    short8 pb0, pb1;                                                         \
    {                                                                        \
      uint* pw_ = (uint*)&pb0;                                               \
      pw_[0] = pkbf(exp2f(fmaf(s0[0], kLOG2E, -kSHIFT)),                     \
                    exp2f(fmaf(s0[1], kLOG2E, -kSHIFT)));                    \
      pw_[1] = pkbf(exp2f(fmaf(s0[2], kLOG2E, -kSHIFT)),                     \
                    exp2f(fmaf(s0[3], kLOG2E, -kSHIFT)));                    \
      pw_[2] = pkbf(exp2f(fmaf(s1[0], kLOG2E, -kSHIFT)),                     \
                    exp2f(fmaf(s1[1], kLOG2E, -kSHIFT)));                    \
      pw_[3] = pkbf(exp2f(fmaf(s1[2], kLOG2E, -kSHIFT)),                     \
                    exp2f(fmaf(s1[3], kLOG2E, -kSHIFT)));                    \
    }                                                                        \
    accy0 = __builtin_amdgcn_mfma_f32_16x16x32_bf16(ga0, pb0, accy0, 0, 0, 0);\
    accy1 = __builtin_amdgcn_mfma_f32_16x16x32_bf16(ga1, pb0, accy1, 0, 0, 0);\
    {                                                                        \
      uint* pw_ = (uint*)&pb1;                                               \
      pw_[0] = pkbf(exp2f(fmaf(s2[0], kLOG2E, -kSHIFT)),                     \
                    exp2f(fmaf(s2[1], kLOG2E, -kSHIFT)));                    \
      pw_[1] = pkbf(exp2f(fmaf(s2[2], kLOG2E, -kSHIFT)),                     \
                    exp2f(fmaf(s2[3], kLOG2E, -kSHIFT)));                    \
      pw_[2] = pkbf(exp2f(fmaf(s3[0], kLOG2E, -kSHIFT)),                     \
                    exp2f(fmaf(s3[1], kLOG2E, -kSHIFT)));                    \
      pw_[3] = pkbf(exp2f(fmaf(s3[2], kLOG2E, -kSHIFT)),                     \
                    exp2f(fmaf(s3[3], kLOG2E, -kSHIFT)));                    \
    }                                                                        \
    accy2 = __builtin_amdgcn_mfma_f32_16x16x32_bf16(ga2, pb0, accy2, 0, 0, 0);\
    accy3 = __builtin_amdgcn_mfma_f32_16x16x32_bf16(ga3, pb0, accy3, 0, 0, 0);\
    accy0 = __builtin_amdgcn_mfma_f32_16x16x32_bf16(ga4, pb1, accy0, 0, 0, 0);\
    accy1 = __builtin_amdgcn_mfma_f32_16x16x32_bf16(ga5, pb1, accy1, 0, 0, 0);\
    accy2 = __builtin_amdgcn_mfma_f32_16x16x32_bf16(ga6, pb1, accy2, 0, 0, 0);\
    accy3 = __builtin_amdgcn_mfma_f32_16x16x32_bf16(ga7, pb1, accy3, 0, 0, 0);\
  }

  f32x4 accy0 = {0.f, 0.f, 0.f, 0.f};
  f32x4 accy1 = {0.f, 0.f, 0.f, 0.f};
  f32x4 accy2 = {0.f, 0.f, 0.f, 0.f};
  f32x4 accy3 = {0.f, 0.f, 0.f, 0.f};

  NLSTAGE(bufA);
  __syncthreads();
#pragma unroll 1
  for (int t = 0; t < 12; ++t) {  // 25 tiles of 64 j
    NLSTAGE(bufB);
    NLCOMP(bufA);
    __syncthreads();
    NLSTAGE(bufA);
    NLCOMP(bufB);
    __syncthreads();
  }
  NLCOMP(bufA);
#undef NLSTAGE
#undef NLCOMP

  // partial y store, bf16, register-linear: [(js,b,itile)][pair*64 + lane]
  ushort* base = (js < 2 ? py01 + (size_t)(js * kB + b) * (kN / 16) * 1024
                         : py23 + (size_t)((js - 2) * kB + b) * (kN / 16) * 1024) +
                 (size_t)itile * 1024;
  uint* b32 = (uint*)base;
  b32[0 * 64 + lane] = pkbf(accy0[0], accy0[1]);
  b32[1 * 64 + lane] = pkbf(accy0[2], accy0[3]);
  b32[2 * 64 + lane] = pkbf(accy1[0], accy1[1]);
  b32[3 * 64 + lane] = pkbf(accy1[2], accy1[3]);
  b32[4 * 64 + lane] = pkbf(accy2[0], accy2[1]);
  b32[5 * 64 + lane] = pkbf(accy2[2], accy2[3]);
  b32[6 * 64 + lane] = pkbf(accy3[0], accy3[1]);
  b32[7 * 64 + lane] = pkbf(accy3[2], accy3[3]);
}

// ---- reduce 4 partials + fused W_y + residuals (R7's verified epilogue).
__global__ __launch_bounds__(128) void k_wy(
    const ushort* __restrict__ py01, const ushort* __restrict__ py23,
    const __hip_bfloat16* __restrict__ wWb, const float* __restrict__ x1,
    const float* __restrict__ alphap, float* __restrict__ z) {
  const int b = blockIdx.y;
  const int lane = threadIdx.x & 63, w = threadIdx.x >> 6;
  const int il = lane & 15, hi = lane >> 4;
  const int itile = blockIdx.x * 2 + w;
  const int iw = itile * 16;

  __shared__ __align__(16) ushort yt2[2][16 * 72];

  const size_t TS = (size_t)(kN / 16) * 1024;
  const uint* p0 = (const uint*)(py01 + (size_t)(0 * kB + b) * TS + itile * 1024);
  const uint* p1 = (const uint*)(py01 + (size_t)(1 * kB + b) * TS + itile * 1024);
  const uint* p2 = (const uint*)(py23 + (size_t)(0 * kB + b) * TS + itile * 1024);
  const uint* p3 = (const uint*)(py23 + (size_t)(1 * kB + b) * TS + itile * 1024);

  float yv[16];
#pragma unroll
  for (int pr = 0; pr < 8; ++pr) {
    const uint u0 = p0[pr * 64 + lane], u1 = p1[pr * 64 + lane];
    const uint u2 = p2[pr * 64 + lane], u3 = p3[pr * 64 + lane];
    yv[2 * pr] = __uint_as_float(u0 << 16) + __uint_as_float(u1 << 16) +
                 __uint_as_float(u2 << 16) + __uint_as_float(u3 << 16);
    yv[2 * pr + 1] = __uint_as_float(u0 & 0xffff0000u) +
                     __uint_as_float(u1 & 0xffff0000u) +
                     __uint_as_float(u2 & 0xffff0000u) +
                     __uint_as_float(u3 & 0xffff0000u);
  }

  ushort* yt = yt2[w];
#pragma unroll
  for (int ct = 0; ct < 4; ++ct) {
    *(uint*)&yt[il * 72 + ct * 16 + hi * 4 + 0] = pkbf(yv[4 * ct], yv[4 * ct + 1]);
    *(uint*)&yt[il * 72 + ct * 16 + hi * 4 + 2] = pkbf(yv[4 * ct + 2], yv[4 * ct + 3]);
  }

  const short8 by0 = *(const short8*)&yt[il * 72 + hi * 8];
  const short8 by1 = *(const short8*)&yt[il * 72 + 32 + hi * 8];
  const float alpha = alphap[0];
#pragma unroll
  for (int q = 0; q < 4; ++q) {
    const short8 af0 = *(const short8*)&wWb[(size_t)(q * 16 + il) * kC + hi * 8];
    const short8 af1 = *(const short8*)&wWb[(size_t)(q * 16 + il) * kC + 32 + hi * 8];
    f32x4 o4 = {0.f, 0.f, 0.f, 0.f};
    o4 = __builtin_amdgcn_mfma_f32_16x16x32_bf16(af0, by0, o4, 0, 0, 0);
    o4 = __builtin_amdgcn_mfma_f32_16x16x32_bf16(af1, by1, o4, 0, 0, 0);
#pragma unroll
    for (int r = 0; r < 4; ++r) {
      const int o = q * 16 + hi * 4 + r;
      const size_t idx = ((size_t)b * kC + o) * kN + iw + il;
      const float xv = x1[idx];
      const float p = xv >= 0.f ? xv : alpha * xv;
      z[idx] = o4[r] + p + xv;
    }
  }
}

extern "C" void kernel_launch(void* const* d_in, const int* in_sizes, int n_in,
                              void* d_out, int out_size, void* d_ws, size_t ws_size,
                              hipStream_t stream) {
  const float* x      = (const float*)d_in[0];
  const float* w1     = (const float*)d_in[1];
  const float* w2     = (const float*)d_in[2];
  const float* wg     = (const float*)d_in[3];
  const float* wth    = (const float*)d_in[4];
  const float* wph    = (const float*)d_in[5];
  const float* wWm    = (const float*)d_in[6];
  const float* alphap = (const float*)d_in[7];
  float* out = (float*)d_out;

  const size_t SZ = (size_t)kB * kC * kN;  // 819200 elements
  float* x1 = (float*)d_ws;                          // [B][C][N] f32
  float* pT = x1 + SZ;                               // [B][N][C] f32; later py01
  __hip_bfloat16* thb = (__hip_bfloat16*)(pT + SZ);  // [B][N][C] bf16; later z
  __hip_bfloat16* phb = thb + SZ;
  __hip_bfloat16* gb  = phb + SZ;
  __hip_bfloat16* gT  = gb + SZ;                     // [B][C][N] bf16 (rs-scaled)
  float* partial = (float*)(gT + SZ);                // [B][4][N] f32
  float* w1t = partial + (size_t)kB * 4 * kN;
  float* w2t = w1t + kC * kC * 9;
  float* wt3 = w2t + kC * kC * 9;
  __hip_bfloat16* wWb = (__hip_bfloat16*)(wt3 + 3 * kC * kC);
  float* py23f = (float*)(wWb + kC * kC);            // SZ f32 region
  ushort* py01 = (ushort*)pT;      // js 0,1 partials (pT dead after k_pw3)
  ushort* py23 = (ushort*)py23f;   // js 2,3 partials
  float* z = (float*)thb;          // thb+phb dead after k_nl; spans SZ f32

  k_prep<<<144, 256, 0, stream>>>(w1, w2, wg, wth, wph, wWm, w1t, w2t,
                                  wt3, wt3 + kC * kC, wt3 + 2 * kC * kC, wWb);
  k_conv3x3<0><<<dim3(25, 4, kB), 256, 0, stream>>>(x, w1t, alphap, x1, pT);
  k_pw3<<<dim3(kN / 64, kB, 3), 64, 0, stream>>>(pT, wt3, thb);
  k_colstat<<<dim3(kN / 32, 4, kB), 128, 0, stream>>>(thb, phb, partial);
  k_gscale<<<dim3(kN / 64, kB), 256, 0, stream>>>(gb, partial, gT);
  k_nl<<<dim3(kN / 32, 4, kB), 128, 0, stream>>>(thb, phb, gT, py01, py23);
  k_wy<<<dim3(kN / 32, kB), 128, 0, stream>>>(py01, py23, wWb, x1, alphap, z);
  k_conv3x3<1><<<dim3(25, 4, kB), 256, 0, stream>>>(z, w2t, alphap, out, nullptr);
}

// Round 9
// 245.598 us; speedup vs baseline: 1.7702x; 1.2335x over previous
//
#include <hip/hip_runtime.h>
#include <hip/hip_bf16.h>
#include <cstddef>

// NLBasicBlock fused, round 9.
// - Bilinear trick: f = p_i^T (Wth^T Wph) p_j, so theta := p (conv1 prelu
//   output, bf16 pixel-major) and phi' = M.p -- one 1x1 GEMM deleted.
// - k_nl / k_colstat: i-tile (j-tile) 32 per wave -> 2x MFMA per staged
//   LDS byte (R8 was LDS/VALU-envelope-bound at 16).
// - split 5 over the streamed dim; partial y summed in k_wy (W_y fused).

constexpr int kB = 2, kC = 64, kH = 80, kW = 80, kN = kH * kW;
constexpr float kLOG2E = 1.4426950408889634f;
constexpr float kSHIFT = 28.853900817779268f;  // 20 * log2(e)

typedef __attribute__((ext_vector_type(8))) short short8;
typedef __attribute__((ext_vector_type(4))) float f32x4;

__device__ __forceinline__ int refl(int i, int n) {
  return i < 0 ? -i : (i >= n ? 2 * n - 2 - i : i);
}

__device__ __forceinline__ uint pkbf(float a, float b) {
  union { __hip_bfloat162 h; uint u; } x;
  x.h.x = __float2bfloat16(a);
  x.h.y = __float2bfloat16(b);
  return x.u;
}

#define GL16(gsrc, ldst)                                                    \
  __builtin_amdgcn_global_load_lds(                                         \
      (__attribute__((address_space(1))) void*)(char*)(gsrc),               \
      (__attribute__((address_space(3))) void*)(ldst), 16, 0, 0)

// ---- conv weight transposes
__global__ void k_prep(const float* __restrict__ w1, const float* __restrict__ w2,
                       float* __restrict__ w1t, float* __restrict__ w2t) {
  int idx = blockIdx.x * 256 + threadIdx.x;
  if (idx < kC * kC * 9) {
    int o = idx / (kC * 9);
    int r = idx % (kC * 9);
    int ci = r / 9, tap = r % 9;
    int d = (ci * 9 + tap) * kC + o;
    w1t[d] = w1[idx];
    w2t[d] = w2[idx];
  }
}

// ---- M = Wth^T . Wph (bf16), plus bf16 copies of Wg, WW
__global__ void k_prepM(const float* __restrict__ wth, const float* __restrict__ wph,
                        const float* __restrict__ wg, const float* __restrict__ wWm,
                        __hip_bfloat16* __restrict__ Mb,
                        __hip_bfloat16* __restrict__ wgb,
                        __hip_bfloat16* __restrict__ wWb) {
  const int idx = blockIdx.x * 256 + threadIdx.x;  // 4096
  const int a = idx >> 6, bb = idx & 63;
  float s = 0.f;
  for (int o = 0; o < kC; ++o) s += wth[o * kC + a] * wph[o * kC + bb];
  Mb[idx] = __float2bfloat16(s);
  wgb[idx] = __float2bfloat16(wg[idx]);
  wWb[idx] = __float2bfloat16(wWm[idx]);
}

// ---- 3x3 reflect conv. MODE 0: raw f32 -> dst_raw [B][C][N] + prelu bf16
// pixel-major -> dst_pt [B][N][C]. MODE 1: prelu f32 -> dst_raw only.
template <int MODE>
__global__ __launch_bounds__(256) void k_conv3x3(
    const float* __restrict__ src, const float* __restrict__ wt,
    const float* __restrict__ alphap, float* __restrict__ dst_raw,
    __hip_bfloat16* __restrict__ dst_pt) {
  const int tile = blockIdx.x;
  const int cog = blockIdx.y;
  const int b = blockIdx.z;
  const int ty0 = (tile / 5) * 16, tx0 = (tile % 5) * 16;
  const int tid = threadIdx.x;
  const int ty = tid / 16, tx = tid % 16;
  const float alpha = alphap[0];

  __shared__ float lds[32 * 18 * 18];
  float acc[16];
#pragma unroll
  for (int o = 0; o < 16; ++o) acc[o] = 0.f;

  for (int chunk = 0; chunk < 2; ++chunk) {
    const int ci0 = chunk * 32;
    __syncthreads();
    for (int idx = tid; idx < 32 * 324; idx += 256) {
      int cc = idx / 324;
      int r = idx % 324;
      int hh = r / 18, ww = r % 18;
      int gh = refl(ty0 - 1 + hh, kH);
      int gw = refl(tx0 - 1 + ww, kW);
      lds[idx] = src[(((size_t)b * kC + ci0 + cc) * kH + gh) * kW + gw];
    }
    __syncthreads();
    for (int cc = 0; cc < 32; ++cc) {
#pragma unroll
      for (int tap = 0; tap < 9; ++tap) {
        const int dh = tap / 3, dw = tap % 3;
        const float xv = lds[cc * 324 + (ty + dh) * 18 + (tx + dw)];
        const float* wr = wt + ((size_t)(ci0 + cc) * 9 + tap) * kC + cog * 16;
#pragma unroll
        for (int o = 0; o < 16; ++o) acc[o] += wr[o] * xv;
      }
    }
  }

  const int n = (ty0 + ty) * kW + (tx0 + tx);
  if (MODE == 0) {
    union { short8 v[2]; uint u[8]; } pk;
#pragma unroll
    for (int o = 0; o < 16; ++o)
      dst_raw[((size_t)b * kC + cog * 16 + o) * kN + n] = acc[o];
#pragma unroll
    for (int q = 0; q < 8; ++q) {
      const float a0 = acc[2 * q], a1 = acc[2 * q + 1];
      pk.u[q] = pkbf(a0 >= 0.f ? a0 : alpha * a0, a1 >= 0.f ? a1 : alpha * a1);
    }
    short8* dp = (short8*)&dst_pt[((size_t)b * kN + n) * kC + cog * 16];
    dp[0] = pk.v[0];
    dp[1] = pk.v[1];
  } else {
#pragma unroll
    for (int o = 0; o < 16; ++o) {
      const float v = acc[o];
      dst_raw[((size_t)b * kC + cog * 16 + o) * kN + n] =
          v >= 0.f ? v : alpha * v;
    }
  }
}

// ---- phi' = M.p and g = Wg.p, both bf16 pixel-major. 4 waves x 16 n.
__global__ __launch_bounds__(256) void k_pw(
    const __hip_bfloat16* __restrict__ pTb, const __hip_bfloat16* __restrict__ Mb,
    const __hip_bfloat16* __restrict__ wgb, __hip_bfloat16* __restrict__ phb,
    __hip_bfloat16* __restrict__ gb) {
  const int b = blockIdx.y;
  const int lane = threadIdx.x & 63, w = threadIdx.x >> 6;
  const int il = lane & 15, hi = lane >> 4;
  const int n = blockIdx.x * 64 + w * 16 + il;

  const short8 b0 = *(const short8*)&pTb[((size_t)b * kN + n) * kC + hi * 8];
  const short8 b1 = *(const short8*)&pTb[((size_t)b * kN + n) * kC + 32 + hi * 8];

#pragma unroll
  for (int q = 0; q < 4; ++q) {
    const short8 am0 = *(const short8*)&Mb[(size_t)(q * 16 + il) * kC + hi * 8];
    const short8 am1 = *(const short8*)&Mb[(size_t)(q * 16 + il) * kC + 32 + hi * 8];
    f32x4 o4 = {0.f, 0.f, 0.f, 0.f};
    o4 = __builtin_amdgcn_mfma_f32_16x16x32_bf16(am0, b0, o4, 0, 0, 0);
    o4 = __builtin_amdgcn_mfma_f32_16x16x32_bf16(am1, b1, o4, 0, 0, 0);
    uint* dp = (uint*)&phb[((size_t)b * kN + n) * kC + q * 16 + hi * 4];
    dp[0] = pkbf(o4[0], o4[1]);
    dp[1] = pkbf(o4[2], o4[3]);
    const short8 ag0 = *(const short8*)&wgb[(size_t)(q * 16 + il) * kC + hi * 8];
    const short8 ag1 = *(const short8*)&wgb[(size_t)(q * 16 + il) * kC + 32 + hi * 8];
    f32x4 g4 = {0.f, 0.f, 0.f, 0.f};
    g4 = __builtin_amdgcn_mfma_f32_16x16x32_bf16(ag0, b0, g4, 0, 0, 0);
    g4 = __builtin_amdgcn_mfma_f32_16x16x32_bf16(ag1, b1, g4, 0, 0, 0);
    uint* dg = (uint*)&gb[((size_t)b * kN + n) * kC + q * 16 + hi * 4];
    dg[0] = pkbf(g4[0], g4[1]);
    dg[1] = pkbf(g4[2], g4[3]);
  }
}

// ---- column sums, j-tile 32/wave, i streamed in 64-tiles (split 5).
__global__ __launch_bounds__(128, 4) void k_colstat(
    const __hip_bfloat16* __restrict__ th, const __hip_bfloat16* __restrict__ ph,
    float* __restrict__ partial) {
  const int b = blockIdx.z, ic = blockIdx.y;
  const int lane = threadIdx.x & 63, w = threadIdx.x >> 6;
  const int il = lane & 15, hi = lane >> 4;
  const int j0w = blockIdx.x * 64 + w * 32;

  __shared__ __align__(16) ushort tbufA[4096], tbufB[4096];

  const __hip_bfloat16* thB = th + (size_t)b * kN * kC;
  const size_t phr0 = ((size_t)b * kN + j0w + il) * kC;
  const size_t phr1 = ((size_t)b * kN + j0w + 16 + il) * kC;
  const short8 a00 = *(const short8*)&ph[phr0 + hi * 8];
  const short8 a01 = *(const short8*)&ph[phr0 + 32 + hi * 8];
  const short8 a10 = *(const short8*)&ph[phr1 + hi * 8];
  const short8 a11 = *(const short8*)&ph[phr1 + 32 + hi * 8];

  const int f0 = 4 * w;
  const char* st[4];
#pragma unroll
  for (int k = 0; k < 4; ++k) {
    const int f = f0 + k;
    st[k] = (const char*)&thB[(size_t)(ic * 1280 + (f >> 1) * 16 + il) * kC +
                              (f & 1) * 32 + hi * 8];
  }

#define CSTAGE(DST)                                                         \
  {                                                                         \
    _Pragma("unroll") for (int k = 0; k < 4; ++k) {                         \
      GL16(st[k], &DST[(f0 + k) * 512]);                                    \
      st[k] += (size_t)64 * kC * 2;                                         \
    }                                                                       \
  }

#define CCOMP(SRC)                                                          \
  {                                                                         \
    const ushort* bp_ = SRC;                                                \
    _Pragma("unroll") for (int s = 0; s < 4; ++s) {                         \
      const short8 bf0 = *(const short8*)&bp_[(2 * s) * 512 + lane * 8];    \
      const short8 bf1 = *(const short8*)&bp_[(2 * s + 1) * 512 + lane * 8];\
      f32x4 sj0 = {0.f, 0.f, 0.f, 0.f};                                     \
      f32x4 sj1 = {0.f, 0.f, 0.f, 0.f};                                     \
      sj0 = __builtin_amdgcn_mfma_f32_16x16x32_bf16(a00, bf0, sj0, 0, 0, 0);\
      sj0 = __builtin_amdgcn_mfma_f32_16x16x32_bf16(a01, bf1, sj0, 0, 0, 0);\
      sj1 = __builtin_amdgcn_mfma_f32_16x16x32_bf16(a10, bf0, sj1, 0, 0, 0);\
      sj1 = __builtin_amdgcn_mfma_f32_16x16x32_bf16(a11, bf1, sj1, 0, 0, 0);\
      _Pragma("unroll") for (int r = 0; r < 4; ++r) {                       \
        cs0[r] += exp2f(fmaf(sj0[r], kLOG2E, -kSHIFT));                     \
        cs1[r] += exp2f(fmaf(sj1[r], kLOG2E, -kSHIFT));                     \
      }                                                                     \
    }                                                                       \
  }

  float cs0[4] = {0.f, 0.f, 0.f, 0.f};
  float cs1[4] = {0.f, 0.f, 0.f, 0.f};
  CSTAGE(tbufA);
  __syncthreads();
#pragma unroll 1
  for (int t = 0; t < 9; ++t) {  // 20 tiles of 64 i
    CSTAGE(tbufB);
    CCOMP(tbufA);
    __syncthreads();
    CSTAGE(tbufA);
    CCOMP(tbufB);
    __syncthreads();
  }
  CSTAGE(tbufB);
  CCOMP(tbufA);
  __syncthreads();
  CCOMP(tbufB);
#undef CSTAGE
#undef CCOMP

#pragma unroll
  for (int r = 0; r < 4; ++r) {
    cs0[r] += __shfl_xor(cs0[r], 1); cs1[r] += __shfl_xor(cs1[r], 1);
    cs0[r] += __shfl_xor(cs0[r], 2); cs1[r] += __shfl_xor(cs1[r], 2);
    cs0[r] += __shfl_xor(cs0[r], 4); cs1[r] += __shfl_xor(cs1[r], 4);
    cs0[r] += __shfl_xor(cs0[r], 8); cs1[r] += __shfl_xor(cs1[r], 8);
  }
  if (il == 0) {
    float* p = partial + (size_t)(b * 5 + ic) * kN + j0w + hi * 4;
#pragma unroll
    for (int r = 0; r < 4; ++r) {
      p[r] = cs0[r];
      p[16 + r] = cs1[r];
    }
  }
}

// ---- gT[b][c][j] = bf16( g[b][j][c] * 1/colsum[b][j] )
__global__ __launch_bounds__(256) void k_gscale(
    const __hip_bfloat16* __restrict__ gb, const float* __restrict__ partial,
    __hip_bfloat16* __restrict__ gT) {
  const int b = blockIdx.y;
  const int j0 = blockIdx.x * 64;
  const int t = threadIdx.x;
  __shared__ ushort tile[64][66];
  __shared__ float rsv[64];
  if (t < 64) {
    const int j = j0 + t;
    float cs = 0.f;
#pragma unroll
    for (int s = 0; s < 5; ++s) cs += partial[(size_t)(b * 5 + s) * kN + j];
    rsv[t] = 1.0f / cs;
  }
  {
    const int jl = t >> 2, cseg = (t & 3) * 16;
    const ushort* src = (const ushort*)&gb[((size_t)b * kN + j0 + jl) * kC + cseg];
    union { short8 v; ushort u[8]; } u0, u1;
    u0.v = *(const short8*)src;
    u1.v = *(const short8*)(src + 8);
#pragma unroll
    for (int k = 0; k < 8; ++k) {
      tile[jl][cseg + k] = u0.u[k];
      tile[jl][cseg + 8 + k] = u1.u[k];
    }
  }
  __syncthreads();
  const int c = t >> 2, jseg = (t & 3) * 16;
  union { short8 v; ushort u[8]; } o0, o1;
#pragma unroll
  for (int k = 0; k < 16; ++k) {
    const int j = jseg + k;
    const float gv = __uint_as_float((uint)tile[j][c] << 16);
    union { __hip_bfloat16 h; ushort us; } cv;
    cv.h = __float2bfloat16(gv * rsv[j]);
    if (k < 8) o0.u[k] = cv.us; else o1.u[k - 8] = cv.us;
  }
  short8* dst = (short8*)&gT[((size_t)b * kC + c) * kN + j0 + jseg];
  dst[0] = o0.v;
  dst[1] = o1.v;
}

// ---- pass B, j-split 5, i-tile 32/wave: partial y bf16 reg-linear.
__global__ __launch_bounds__(128, 2) void k_nl(
    const __hip_bfloat16* __restrict__ th, const __hip_bfloat16* __restrict__ ph,
    const __hip_bfloat16* __restrict__ gT, ushort* __restrict__ py) {
  const int js = blockIdx.y, b = blockIdx.z;
  const int lane = threadIdx.x & 63, w = threadIdx.x >> 6;
  const int il = lane & 15, hi = lane >> 4;
  const int itile32 = blockIdx.x * 2 + w;
  const int i0w = itile32 * 32;
  const int jstart = js * 1280;
  const int jbase = ((il >> 2) << 3) + (il & 3);  // sigma(row=il)

  __shared__ __align__(16) ushort bufA[8192], bufB[8192];  // [phi 8K|gT 8K]

  const __hip_bfloat16* phB = ph + (size_t)b * kN * kC;
  const __hip_bfloat16* gTB = gT + (size_t)b * kC * kN;

  const size_t tr0 = ((size_t)b * kN + i0w + il) * kC;
  const size_t tr1 = ((size_t)b * kN + i0w + 16 + il) * kC;
  const short8 tA0k0 = *(const short8*)&th[tr0 + hi * 8];
  const short8 tA0k1 = *(const short8*)&th[tr0 + 32 + hi * 8];
  const short8 tA1k0 = *(const short8*)&th[tr1 + hi * 8];
  const short8 tA1k1 = *(const short8*)&th[tr1 + 32 + hi * 8];

  const int f0 = 4 * w;
  const char* sp[4];
  const char* sg[4];
#pragma unroll
  for (int k = 0; k < 4; ++k) {
    const int f = f0 + k;
    const int pr = jstart + jbase + ((f >> 1) & 1) * 4 + ((f >> 2) & 1) * 32;
    const int pc = (f & 1) * 32 + hi * 8;
    sp[k] = (const char*)&phB[(size_t)pr * kC + pc];
    const int gc = (f & 3) * 16 + il;
    const int gj = jstart + ((f >> 2) & 1) * 32 + hi * 8;
    sg[k] = (const char*)&gTB[(size_t)gc * kN + gj];
  }

#define NLSTAGE(DST)                                                        \
  {                                                                         \
    _Pragma("unroll") for (int k = 0; k < 4; ++k) {                         \
      GL16(sp[k], &DST[(f0 + k) * 512]);                                    \
      GL16(sg[k], &DST[4096 + (f0 + k) * 512]);                             \
      sp[k] += (size_t)64 * kC * 2;                                         \
      sg[k] += (size_t)64 * 2;                                              \
    }                                                                       \
  }

#define QKI(S, TB0, TB1, s0, s1, s2, s3)                                     \
    f32x4 s0 = {0.f, 0.f, 0.f, 0.f};                                         \
    f32x4 s1 = {0.f, 0.f, 0.f, 0.f};                                         \
    f32x4 s2 = {0.f, 0.f, 0.f, 0.f};                                         \
    f32x4 s3 = {0.f, 0.f, 0.f, 0.f};                                         \
    s0 = __builtin_amdgcn_mfma_f32_16x16x32_bf16(pa0, TB0, s0, 0, 0, 0);     \
    s0 = __builtin_amdgcn_mfma_f32_16x16x32_bf16(pa1, TB1, s0, 0, 0, 0);     \
    s1 = __builtin_amdgcn_mfma_f32_16x16x32_bf16(pa2, TB0, s1, 0, 0, 0);     \
    s1 = __builtin_amdgcn_mfma_f32_16x16x32_bf16(pa3, TB1, s1, 0, 0, 0);     \
    s2 = __builtin_amdgcn_mfma_f32_16x16x32_bf16(pa4, TB0, s2, 0, 0, 0);     \
    s2 = __builtin_amdgcn_mfma_f32_16x16x32_bf16(pa5, TB1, s2, 0, 0, 0);     \
    s3 = __builtin_amdgcn_mfma_f32_16x16x32_bf16(pa6, TB0, s3, 0, 0, 0);     \
    s3 = __builtin_amdgcn_mfma_f32_16x16x32_bf16(pa7, TB1, s3, 0, 0, 0);

#define PACK2(sa, sb, pb)                                                    \
    short8 pb;                                                               \
    {                                                                        \
      uint* pw_ = (uint*)&pb;                                                \
      pw_[0] = pkbf(exp2f(fmaf(sa[0], kLOG2E, -kSHIFT)),                     \
                    exp2f(fmaf(sa[1], kLOG2E, -kSHIFT)));                    \
      pw_[1] = pkbf(exp2f(fmaf(sa[2], kLOG2E, -kSHIFT)),                     \
                    exp2f(fmaf(sa[3], kLOG2E, -kSHIFT)));                    \
      pw_[2] = pkbf(exp2f(fmaf(sb[0], kLOG2E, -kSHIFT)),                     \
                    exp2f(fmaf(sb[1], kLOG2E, -kSHIFT)));                    \
      pw_[3] = pkbf(exp2f(fmaf(sb[2], kLOG2E, -kSHIFT)),                     \
                    exp2f(fmaf(sb[3], kLOG2E, -kSHIFT)));                    \
    }

#define NLCOMP(SRC)                                                          \
  {                                                                          \
    const ushort* bp_ = SRC;                                                 \
    const short8 pa0 = *(const short8*)&bp_[0 * 512 + lane * 8];             \
    const short8 pa1 = *(const short8*)&bp_[1 * 512 + lane * 8];             \
    const short8 pa2 = *(const short8*)&bp_[2 * 512 + lane * 8];             \
    const short8 pa3 = *(const short8*)&bp_[3 * 512 + lane * 8];             \
    const short8 pa4 = *(const short8*)&bp_[4 * 512 + lane * 8];             \
    const short8 pa5 = *(const short8*)&bp_[5 * 512 + lane * 8];             \
    const short8 pa6 = *(const short8*)&bp_[6 * 512 + lane * 8];             \
    const short8 pa7 = *(const short8*)&bp_[7 * 512 + lane * 8];             \
    const short8 ga0 = *(const short8*)&bp_[4096 + 0 * 512 + lane * 8];      \
    const short8 ga1 = *(const short8*)&bp_[4096 + 1 * 512 + lane * 8];      \
    const short8 ga2 = *(const short8*)&bp_[4096 + 2 * 512 + lane * 8];      \
    const short8 ga3 = *(const short8*)&bp_[4096 + 3 * 512 + lane * 8];      \
    const short8 ga4 = *(const short8*)&bp_[4096 + 4 * 512 + lane * 8];      \
    const short8 ga5 = *(const short8*)&bp_[4096 + 5 * 512 + lane * 8];      \
    const short8 ga6 = *(const short8*)&bp_[4096 + 6 * 512 + lane * 8];      \
    const short8 ga7 = *(const short8*)&bp_[4096 + 7 * 512 + lane * 8];      \
    {                                                                        \
      QKI(SRC, tA0k0, tA0k1, s00, s01, s02, s03)                             \
      PACK2(s00, s01, pb00)                                                  \
      PACK2(s02, s03, pb01)                                                  \
      ay00 = __builtin_amdgcn_mfma_f32_16x16x32_bf16(ga0, pb00, ay00, 0, 0, 0);\
      ay01 = __builtin_amdgcn_mfma_f32_16x16x32_bf16(ga1, pb00, ay01, 0, 0, 0);\
      ay02 = __builtin_amdgcn_mfma_f32_16x16x32_bf16(ga2, pb00, ay02, 0, 0, 0);\
      ay03 = __builtin_amdgcn_mfma_f32_16x16x32_bf16(ga3, pb00, ay03, 0, 0, 0);\
      ay00 = __builtin_amdgcn_mfma_f32_16x16x32_bf16(ga4, pb01, ay00, 0, 0, 0);\
      ay01 = __builtin_amdgcn_mfma_f32_16x16x32_bf16(ga5, pb01, ay01, 0, 0, 0);\
      ay02 = __builtin_amdgcn_mfma_f32_16x16x32_bf16(ga6, pb01, ay02, 0, 0, 0);\
      ay03 = __builtin_amdgcn_mfma_f32_16x16x32_bf16(ga7, pb01, ay03, 0, 0, 0);\
    }                                                                        \
    {                                                                        \
      QKI(SRC, tA1k0, tA1k1, s10, s11, s12, s13)                             \
      PACK2(s10, s11, pb10)                                                  \
      PACK2(s12, s13, pb11)                                                  \
      ay10 = __builtin_amdgcn_mfma_f32_16x16x32_bf16(ga0, pb10, ay10, 0, 0, 0);\
      ay11 = __builtin_amdgcn_mfma_f32_16x16x32_bf16(ga1, pb10, ay11, 0, 0, 0);\
      ay12 = __builtin_amdgcn_mfma_f32_16x16x32_bf16(ga2, pb10, ay12, 0, 0, 0);\
      ay13 = __builtin_amdgcn_mfma_f32_16x16x32_bf16(ga3, pb10, ay13, 0, 0, 0);\
      ay10 = __builtin_amdgcn_mfma_f32_16x16x32_bf16(ga4, pb11, ay10, 0, 0, 0);\
      ay11 = __builtin_amdgcn_mfma_f32_16x16x32_bf16(ga5, pb11, ay11, 0, 0, 0);\
      ay12 = __builtin_amdgcn_mfma_f32_16x16x32_bf16(ga6, pb11, ay12, 0, 0, 0);\
      ay13 = __builtin_amdgcn_mfma_f32_16x16x32_bf16(ga7, pb11, ay13, 0, 0, 0);\
    }                                                                        \
  }

  f32x4 ay00 = {0.f, 0.f, 0.f, 0.f}, ay01 = {0.f, 0.f, 0.f, 0.f};
  f32x4 ay02 = {0.f, 0.f, 0.f, 0.f}, ay03 = {0.f, 0.f, 0.f, 0.f};
  f32x4 ay10 = {0.f, 0.f, 0.f, 0.f}, ay11 = {0.f, 0.f, 0.f, 0.f};
  f32x4 ay12 = {0.f, 0.f, 0.f, 0.f}, ay13 = {0.f, 0.f, 0.f, 0.f};

  NLSTAGE(bufA);
  __syncthreads();
#pragma unroll 1
  for (int t = 0; t < 9; ++t) {  // 20 tiles of 64 j
    NLSTAGE(bufB);
    NLCOMP(bufA);
    __syncthreads();
    NLSTAGE(bufA);
    NLCOMP(bufB);
    __syncthreads();
  }
  NLSTAGE(bufB);
  NLCOMP(bufA);
  __syncthreads();
  NLCOMP(bufB);
#undef NLSTAGE
#undef NLCOMP
#undef QKI
#undef PACK2

  // partial y store: [(js*kB+b)*(kN/32)+itile32] tile of 2048 ushorts,
  // k = a*8 + ct*2 + u at [k*64 + lane]
  uint* b32 = (uint*)(py + ((size_t)(js * kB + b) * (kN / 32) + itile32) * 2048);
  b32[0 * 64 + lane] = pkbf(ay00[0], ay00[1]);
  b32[1 * 64 + lane] = pkbf(ay00[2], ay00[3]);
  b32[2 * 64 + lane] = pkbf(ay01[0], ay01[1]);
  b32[3 * 64 + lane] = pkbf(ay01[2], ay01[3]);
  b32[4 * 64 + lane] = pkbf(ay02[0], ay02[1]);
  b32[5 * 64 + lane] = pkbf(ay02[2], ay02[3]);
  b32[6 * 64 + lane] = pkbf(ay03[0], ay03[1]);
  b32[7 * 64 + lane] = pkbf(ay03[2], ay03[3]);
  b32[8 * 64 + lane] = pkbf(ay10[0], ay10[1]);
  b32[9 * 64 + lane] = pkbf(ay10[2], ay10[3]);
  b32[10 * 64 + lane] = pkbf(ay11[0], ay11[1]);
  b32[11 * 64 + lane] = pkbf(ay11[2], ay11[3]);
  b32[12 * 64 + lane] = pkbf(ay12[0], ay12[1]);
  b32[13 * 64 + lane] = pkbf(ay12[2], ay12[3]);
  b32[14 * 64 + lane] = pkbf(ay13[0], ay13[1]);
  b32[15 * 64 + lane] = pkbf(ay13[2], ay13[3]);
}

// ---- reduce 5 partials + fused W_y + residuals. Wave = 32 i.
__global__ __launch_bounds__(128) void k_wy(
    const ushort* __restrict__ py, const __hip_bfloat16* __restrict__ wWb,
    const float* __restrict__ x1, const float* __restrict__ alphap,
    float* __restrict__ z) {
  const int b = blockIdx.y;
  const int lane = threadIdx.x & 63, w = threadIdx.x >> 6;
  const int il = lane & 15, hi = lane >> 4;
  const int itile32 = blockIdx.x * 2 + w;
  const int i0w = itile32 * 32;

  __shared__ __align__(16) ushort yt2[2][32 * 72];
  ushort* yt = yt2[w];

  const uint* p[5];
#pragma unroll
  for (int s = 0; s < 5; ++s)
    p[s] = (const uint*)(py + ((size_t)(s * kB + b) * (kN / 32) + itile32) * 2048);

#pragma unroll
  for (int k = 0; k < 16; ++k) {
    float lo = 0.f, hs = 0.f;
#pragma unroll
    for (int s = 0; s < 5; ++s) {
      const uint u = p[s][k * 64 + lane];
      lo += __uint_as_float(u << 16);
      hs += __uint_as_float(u & 0xffff0000u);
    }
    const int row = (k >> 3) * 16 + il;
    const int col = ((k >> 1) & 3) * 16 + hi * 4 + (k & 1) * 2;
    *(uint*)&yt[row * 72 + col] = pkbf(lo, hs);
  }

  const float alpha = alphap[0];
#pragma unroll
  for (int a = 0; a < 2; ++a) {
    const short8 by0 = *(const short8*)&yt[(a * 16 + il) * 72 + hi * 8];
    const short8 by1 = *(const short8*)&yt[(a * 16 + il) * 72 + 32 + hi * 8];
#pragma unroll
    for (int q = 0; q < 4; ++q) {
      const short8 af0 = *(const short8*)&wWb[(size_t)(q * 16 + il) * kC + hi * 8];
      const short8 af1 = *(const short8*)&wWb[(size_t)(q * 16 + il) * kC + 32 + hi * 8];
      f32x4 o4 = {0.f, 0.f, 0.f, 0.f};
      o4 = __builtin_amdgcn_mfma_f32_16x16x32_bf16(af0, by0, o4, 0, 0, 0);
      o4 = __builtin_amdgcn_mfma_f32_16x16x32_bf16(af1, by1, o4, 0, 0, 0);
#pragma unroll
      for (int r = 0; r < 4; ++r) {
        const int o = q * 16 + hi * 4 + r;
        const size_t idx = ((size_t)b * kC + o) * kN + i0w + a * 16 + il;
        const float xv = x1[idx];
        const float pr = xv >= 0.f ? xv : alpha * xv;
        z[idx] = o4[r] + pr + xv;
      }
    }
  }
}

extern "C" void kernel_launch(void* const* d_in, const int* in_sizes, int n_in,
                              void* d_out, int out_size, void* d_ws, size_t ws_size,
                              hipStream_t stream) {
  const float* x      = (const float*)d_in[0];
  const float* w1     = (const float*)d_in[1];
  const float* w2     = (const float*)d_in[2];
  const float* wg     = (const float*)d_in[3];
  const float* wth    = (const float*)d_in[4];
  const float* wph    = (const float*)d_in[5];
  const float* wWm    = (const float*)d_in[6];
  const float* alphap = (const float*)d_in[7];
  float* out = (float*)d_out;

  const size_t SZ = (size_t)kB * kC * kN;  // 819200 elements
  float* x1 = (float*)d_ws;                              // [B][C][N] f32
  __hip_bfloat16* pTb = (__hip_bfloat16*)(x1 + SZ);      // [B][N][C] bf16
  __hip_bfloat16* phb = pTb + SZ;                        // [B][N][C] bf16 (M.p)
  __hip_bfloat16* gb  = phb + SZ;                        // [B][N][C] bf16
  __hip_bfloat16* gT  = gb + SZ;                         // [B][C][N] bf16 scaled
  float* partial = (float*)(gT + SZ);                    // [B][5][N] f32
  float* w1t = partial + (size_t)kB * 5 * kN;
  float* w2t = w1t + kC * kC * 9;
  __hip_bfloat16* Mb  = (__hip_bfloat16*)(w2t + kC * kC * 9);
  __hip_bfloat16* wgb = Mb + kC * kC;
  __hip_bfloat16* wWb = wgb + kC * kC;
  ushort* py = (ushort*)(wWb + kC * kC);                 // 5*B*(N/32)*2048 ushort
  float* z = (float*)phb;  // phb/gb/gT dead by k_wy; 1.5*SZ floats >= SZ

  k_prep<<<144, 256, 0, stream>>>(w1, w2, w1t, w2t);
  k_prepM<<<16, 256, 0, stream>>>(wth, wph, wg, wWm, Mb, wgb, wWb);
  k_conv3x3<0><<<dim3(25, 4, kB), 256, 0, stream>>>(x, w1t, alphap, x1, pTb);
  k_pw<<<dim3(kN / 64, kB), 256, 0, stream>>>(pTb, Mb, wgb, phb, gb);
  k_colstat<<<dim3(kN / 64, 5, kB), 128, 0, stream>>>(pTb, phb, partial);
  k_gscale<<<dim3(kN / 64, kB), 256, 0, stream>>>(gb, partial, gT);
  k_nl<<<dim3(kN / 64, 5, kB), 128, 0, stream>>>(pTb, phb, gT, py);
  k_wy<<<dim3(kN / 64, kB), 128, 0, stream>>>(py, wWb, x1, alphap, z);
  k_conv3x3<1><<<dim3(25, 4, kB), 256, 0, stream>>>(z, w2t, alphap, out,
                                                    (__hip_bfloat16*)nullptr);
}

// Round 10
// 134.262 us; speedup vs baseline: 3.2381x; 1.8292x over previous
//
#include <hip/hip_runtime.h>
#include <hip/hip_bf16.h>
#include <cstddef>

// NLBasicBlock fused, round 10: convs moved to MFMA (implicit GEMM, 9 taps x
// 2 K-chunks; weights pre-packed fragment-linear and held in VGPRs; per-lane
// reflect-shifted global A reads, no LDS staging). Nonlocal path as R9.

constexpr int kB = 2, kC = 64, kH = 80, kW = 80, kN = kH * kW;
constexpr float kLOG2E = 1.4426950408889634f;
constexpr float kSHIFT = 28.853900817779268f;  // 20 * log2(e)

typedef __attribute__((ext_vector_type(8))) short short8;
typedef __attribute__((ext_vector_type(4))) float f32x4;

__device__ __forceinline__ uint pkbf(float a, float b) {
  union { __hip_bfloat162 h; uint u; } x;
  x.h.x = __float2bfloat16(a);
  x.h.y = __float2bfloat16(b);
  return x.u;
}

#define GL16(gsrc, ldst)                                                    \
  __builtin_amdgcn_global_load_lds(                                         \
      (__attribute__((address_space(1))) void*)(char*)(gsrc),               \
      (__attribute__((address_space(3))) void*)(ldst), 16, 0, 0)

// ---- conv weights -> bf16 MFMA B-fragment-linear: frag=(tap*2+kc)*4+og,
// element (hi*16+il)*8+e  <=>  w[og*16+il][kc*32+hi*8+e] at tap.
__global__ void k_prep(const float* __restrict__ w1, const float* __restrict__ w2,
                       ushort* __restrict__ wc1, ushort* __restrict__ wc2) {
  const int idx = blockIdx.x * 256 + threadIdx.x;  // 36864
  const int o = idx / (kC * 9);
  const int r = idx % (kC * 9);
  const int ci = r / 9, tap = r % 9;
  const int og = o >> 4, il = o & 15;
  const int kc = ci >> 5, hi = (ci >> 3) & 3, e = ci & 7;
  const int pos = ((tap * 2 + kc) * 4 + og) * 512 + (hi * 16 + il) * 8 + e;
  union { __hip_bfloat16 h; ushort u; } c1, c2;
  c1.h = __float2bfloat16(w1[idx]);
  c2.h = __float2bfloat16(w2[idx]);
  wc1[pos] = c1.u;
  wc2[pos] = c2.u;
}

// ---- M = Wth^T.Wph (bf16) + bf16 Wg, WW
__global__ void k_prepM(const float* __restrict__ wth, const float* __restrict__ wph,
                        const float* __restrict__ wg, const float* __restrict__ wWm,
                        __hip_bfloat16* __restrict__ Mb,
                        __hip_bfloat16* __restrict__ wgb,
                        __hip_bfloat16* __restrict__ wWb) {
  const int idx = blockIdx.x * 256 + threadIdx.x;  // 4096
  const int a = idx >> 6, bb = idx & 63;
  float s = 0.f;
  for (int o = 0; o < kC; ++o) s += wth[o * kC + a] * wph[o * kC + bb];
  Mb[idx] = __float2bfloat16(s);
  wgb[idx] = __float2bfloat16(wg[idx]);
  wWb[idx] = __float2bfloat16(wWm[idx]);
}

// ---- x f32 [B][C][N] -> bf16 pixel-major [B][N][C]
__global__ __launch_bounds__(256) void k_tobf(const float* __restrict__ x,
                                              ushort* __restrict__ xb) {
  const int b = blockIdx.y;
  const int j0 = blockIdx.x * 64;
  const int t = threadIdx.x;
  __shared__ ushort tile[64][68];
  {
    const int c = t >> 2, jseg = (t & 3) * 16;
    const float* s = &x[((size_t)b * kC + c) * kN + j0 + jseg];
#pragma unroll
    for (int k = 0; k < 16; ++k) {
      union { __hip_bfloat16 h; ushort u; } cv;
      cv.h = __float2bfloat16(s[k]);
      tile[c][jseg + k] = cv.u;
    }
  }
  __syncthreads();
  {
    const int j = t >> 2, cseg = (t & 3) * 16;
    union { short8 v; ushort u[8]; } o0, o1;
#pragma unroll
    for (int k = 0; k < 16; ++k) {
      const ushort u = tile[cseg + k][j];
      if (k < 8) o0.u[k] = u; else o1.u[k - 8] = u;
    }
    short8* d = (short8*)&xb[((size_t)b * kN + j0 + j) * kC + cseg];
    d[0] = o0.v;
    d[1] = o1.v;
  }
}

// ---- MFMA 3x3 reflect conv. Block = 16 px, 4 waves (one per 16-out group).
// MODE 0: raw f32 [B][C][N] + prelu bf16 pixel-major. MODE 1: prelu f32 only.
template <int MODE>
__global__ __launch_bounds__(256) void k_convm(
    const ushort* __restrict__ xb, const ushort* __restrict__ wc,
    const float* __restrict__ alphap, float* __restrict__ raw,
    ushort* __restrict__ pt) {
  const int tile = blockIdx.x;  // 400 = 80 rows x 5 col-tiles
  const int b = blockIdx.y;
  const int r0 = tile / 5, c0 = (tile % 5) * 16;
  const int lane = threadIdx.x & 63, w = threadIdx.x >> 6;
  const int il = lane & 15, hi = lane >> 4;

  __shared__ ushort zt[16][72];

  // weight fragments for this wave's out-group, held in VGPRs
  short8 wt[9][2];
#pragma unroll
  for (int t = 0; t < 9; ++t)
#pragma unroll
    for (int kc = 0; kc < 2; ++kc)
      wt[t][kc] = *(const short8*)&wc[(size_t)((t * 2 + kc) * 4 + w) * 512 + lane * 8];

  // per-lane reflect addresses
  int cl[3], rb[3];
#pragma unroll
  for (int d = 0; d < 3; ++d) {
    const int cc = c0 + il + d - 1;
    cl[d] = cc < 0 ? 1 : (cc > kW - 1 ? kW - 2 : cc);
    const int rr = r0 + d - 1;
    rb[d] = rr < 0 ? 1 : (rr > kH - 1 ? kH - 2 : rr);
  }
  const ushort* xB = xb + (size_t)b * kN * kC;

  f32x4 acc = {0.f, 0.f, 0.f, 0.f};
#pragma unroll
  for (int dh = 0; dh < 3; ++dh) {
    const int nb = rb[dh] * kW;
#pragma unroll
    for (int dw = 0; dw < 3; ++dw) {
      const ushort* src = &xB[(size_t)(nb + cl[dw]) * kC + hi * 8];
      const short8 a0 = *(const short8*)src;
      const short8 a1 = *(const short8*)(src + 32);
      acc = __builtin_amdgcn_mfma_f32_16x16x32_bf16(a0, wt[dh * 3 + dw][0], acc, 0, 0, 0);
      acc = __builtin_amdgcn_mfma_f32_16x16x32_bf16(a1, wt[dh * 3 + dw][1], acc, 0, 0, 0);
    }
  }

  // D: lane holds o = w*16+il, pixels hi*4+r
  const int n0 = r0 * kW + c0;
  const float alpha = alphap[0];
  if (MODE == 0) {
    *(f32x4*)&raw[((size_t)b * kC + w * 16 + il) * kN + n0 + hi * 4] = acc;
#pragma unroll
    for (int r = 0; r < 4; ++r) {
      const float v = acc[r];
      union { __hip_bfloat16 h; ushort u; } cv;
      cv.h = __float2bfloat16(v >= 0.f ? v : alpha * v);
      zt[hi * 4 + r][w * 16 + il] = cv.u;
    }
    __syncthreads();
    const int t = threadIdx.x;
    const int px = t >> 4, cb = (t & 15) * 4;
    uint2 o2;
    o2.x = (uint)zt[px][cb] | ((uint)zt[px][cb + 1] << 16);
    o2.y = (uint)zt[px][cb + 2] | ((uint)zt[px][cb + 3] << 16);
    *(uint2*)&pt[((size_t)b * kN + n0 + px) * kC + cb] = o2;
  } else {
    f32x4 pr;
#pragma unroll
    for (int r = 0; r < 4; ++r) {
      const float v = acc[r];
      pr[r] = v >= 0.f ? v : alpha * v;
    }
    *(f32x4*)&raw[((size_t)b * kC + w * 16 + il) * kN + n0 + hi * 4] = pr;
  }
}

// ---- phi' = M.p, g = Wg.p (bf16 pixel-major). Block = 16 px, wave = q-group.
__global__ __launch_bounds__(256) void k_pw(
    const __hip_bfloat16* __restrict__ pTb, const __hip_bfloat16* __restrict__ Mb,
    const __hip_bfloat16* __restrict__ wgb, __hip_bfloat16* __restrict__ phb,
    __hip_bfloat16* __restrict__ gb) {
  const int b = blockIdx.y;
  const int lane = threadIdx.x & 63, w = threadIdx.x >> 6;
  const int il = lane & 15, hi = lane >> 4;
  const int n = blockIdx.x * 16 + il;

  const short8 b0 = *(const short8*)&pTb[((size_t)b * kN + n) * kC + hi * 8];
  const short8 b1 = *(const short8*)&pTb[((size_t)b * kN + n) * kC + 32 + hi * 8];

  const short8 am0 = *(const short8*)&Mb[(size_t)(w * 16 + il) * kC + hi * 8];
  const short8 am1 = *(const short8*)&Mb[(size_t)(w * 16 + il) * kC + 32 + hi * 8];
  f32x4 o4 = {0.f, 0.f, 0.f, 0.f};
  o4 = __builtin_amdgcn_mfma_f32_16x16x32_bf16(am0, b0, o4, 0, 0, 0);
  o4 = __builtin_amdgcn_mfma_f32_16x16x32_bf16(am1, b1, o4, 0, 0, 0);
  uint2 p2;
  p2.x = pkbf(o4[0], o4[1]);
  p2.y = pkbf(o4[2], o4[3]);
  *(uint2*)&phb[((size_t)b * kN + n) * kC + w * 16 + hi * 4] = p2;

  const short8 ag0 = *(const short8*)&wgb[(size_t)(w * 16 + il) * kC + hi * 8];
  const short8 ag1 = *(const short8*)&wgb[(size_t)(w * 16 + il) * kC + 32 + hi * 8];
  f32x4 g4 = {0.f, 0.f, 0.f, 0.f};
  g4 = __builtin_amdgcn_mfma_f32_16x16x32_bf16(ag0, b0, g4, 0, 0, 0);
  g4 = __builtin_amdgcn_mfma_f32_16x16x32_bf16(ag1, b1, g4, 0, 0, 0);
  uint2 g2;
  g2.x = pkbf(g4[0], g4[1]);
  g2.y = pkbf(g4[2], g4[3]);
  *(uint2*)&gb[((size_t)b * kN + n) * kC + w * 16 + hi * 4] = g2;
}

// ---- column sums, j-tile 32/wave, i streamed 64-tiles, split 5 (R9).
__global__ __launch_bounds__(128, 4) void k_colstat(
    const __hip_bfloat16* __restrict__ th, const __hip_bfloat16* __restrict__ ph,
    float* __restrict__ partial) {
  const int b = blockIdx.z, ic = blockIdx.y;
  const int lane = threadIdx.x & 63, w = threadIdx.x >> 6;
  const int il = lane & 15, hi = lane >> 4;
  const int j0w = blockIdx.x * 64 + w * 32;

  __shared__ __align__(16) ushort tbufA[4096], tbufB[4096];

  const __hip_bfloat16* thB = th + (size_t)b * kN * kC;
  const size_t phr0 = ((size_t)b * kN + j0w + il) * kC;
  const size_t phr1 = ((size_t)b * kN + j0w + 16 + il) * kC;
  const short8 a00 = *(const short8*)&ph[phr0 + hi * 8];
  const short8 a01 = *(const short8*)&ph[phr0 + 32 + hi * 8];
  const short8 a10 = *(const short8*)&ph[phr1 + hi * 8];
  const short8 a11 = *(const short8*)&ph[phr1 + 32 + hi * 8];

  const int f0 = 4 * w;
  const char* st[4];
#pragma unroll
  for (int k = 0; k < 4; ++k) {
    const int f = f0 + k;
    st[k] = (const char*)&thB[(size_t)(ic * 1280 + (f >> 1) * 16 + il) * kC +
                              (f & 1) * 32 + hi * 8];
  }

#define CSTAGE(DST)                                                         \
  {                                                                         \
    _Pragma("unroll") for (int k = 0; k < 4; ++k) {                         \
      GL16(st[k], &DST[(f0 + k) * 512]);                                    \
      st[k] += (size_t)64 * kC * 2;                                         \
    }                                                                       \
  }

#define CCOMP(SRC)                                                         \
  {                                                                        \
    const ushort* bp_ = SRC;                                               \
    _Pragma("unroll") for (int s = 0; s < 4; ++s) {                        \
      const short8 bf0 = *(const short8*)&bp_[(2 * s) * 512 + lane * 8];   \
      const short8 bf1 = *(const short8*)&bp_[(2 * s + 1) * 512 + lane * 8];\
      f32x4 sj0 = {0.f, 0.f, 0.f, 0.f};                                    \
      f32x4 sj1 = {0.f, 0.f, 0.f, 0.f};                                    \
      sj0 = __builtin_amdgcn_mfma_f32_16x16x32_bf16(a00, bf0, sj0, 0, 0, 0);\
      sj0 = __builtin_amdgcn_mfma_f32_16x16x32_bf16(a01, bf1, sj0, 0, 0, 0);\
      sj1 = __builtin_amdgcn_mfma_f32_16x16x32_bf16(a10, bf0, sj1, 0, 0, 0);\
      sj1 = __builtin_amdgcn_mfma_f32_16x16x32_bf16(a11, bf1, sj1, 0, 0, 0);\
      _Pragma("unroll") for (int r = 0; r < 4; ++r) {                      \
        cs0[r] += exp2f(fmaf(sj0[r], kLOG2E, -kSHIFT));                    \
        cs1[r] += exp2f(fmaf(sj1[r], kLOG2E, -kSHIFT));                    \
      }                                                                    \
    }                                                                      \
  }

  float cs0[4] = {0.f, 0.f, 0.f, 0.f};
  float cs1[4] = {0.f, 0.f, 0.f, 0.f};
  CSTAGE(tbufA);
  __syncthreads();
#pragma unroll 1
  for (int t = 0; t < 9; ++t) {
    CSTAGE(tbufB);
    CCOMP(tbufA);
    __syncthreads();
    CSTAGE(tbufA);
    CCOMP(tbufB);
    __syncthreads();
  }
  CSTAGE(tbufB);
  CCOMP(tbufA);
  __syncthreads();
  CCOMP(tbufB);
#undef CSTAGE
#undef CCOMP

#pragma unroll
  for (int r = 0; r < 4; ++r) {
    cs0[r] += __shfl_xor(cs0[r], 1); cs1[r] += __shfl_xor(cs1[r], 1);
    cs0[r] += __shfl_xor(cs0[r], 2); cs1[r] += __shfl_xor(cs1[r], 2);
    cs0[r] += __shfl_xor(cs0[r], 4); cs1[r] += __shfl_xor(cs1[r], 4);
    cs0[r] += __shfl_xor(cs0[r], 8); cs1[r] += __shfl_xor(cs1[r], 8);
  }
  if (il == 0) {
    float* p = partial + (size_t)(b * 5 + ic) * kN + j0w + hi * 4;
#pragma unroll
    for (int r = 0; r < 4; ++r) {
      p[r] = cs0[r];
      p[16 + r] = cs1[r];
    }
  }
}

// ---- gT[b][c][j] = bf16( g[b][j][c] * 1/colsum[b][j] )
__global__ __launch_bounds__(256) void k_gscale(
    const __hip_bfloat16* __restrict__ gb, const float* __restrict__ partial,
    __hip_bfloat16* __restrict__ gT) {
  const int b = blockIdx.y;
  const int j0 = blockIdx.x * 64;
  const int t = threadIdx.x;
  __shared__ ushort tile[64][66];
  __shared__ float rsv[64];
  if (t < 64) {
    const int j = j0 + t;
    float cs = 0.f;
#pragma unroll
    for (int s = 0; s < 5; ++s) cs += partial[(size_t)(b * 5 + s) * kN + j];
    rsv[t] = 1.0f / cs;
  }
  {
    const int jl = t >> 2, cseg = (t & 3) * 16;
    const ushort* src = (const ushort*)&gb[((size_t)b * kN + j0 + jl) * kC + cseg];
    union { short8 v; ushort u[8]; } u0, u1;
    u0.v = *(const short8*)src;
    u1.v = *(const short8*)(src + 8);
#pragma unroll
    for (int k = 0; k < 8; ++k) {
      tile[jl][cseg + k] = u0.u[k];
      tile[jl][cseg + 8 + k] = u1.u[k];
    }
  }
  __syncthreads();
  const int c = t >> 2, jseg = (t & 3) * 16;
  union { short8 v; ushort u[8]; } o0, o1;
#pragma unroll
  for (int k = 0; k < 16; ++k) {
    const int j = jseg + k;
    const float gv = __uint_as_float((uint)tile[j][c] << 16);
    union { __hip_bfloat16 h; ushort us; } cv;
    cv.h = __float2bfloat16(gv * rsv[j]);
    if (k < 8) o0.u[k] = cv.us; else o1.u[k - 8] = cv.us;
  }
  short8* dst = (short8*)&gT[((size_t)b * kC + c) * kN + j0 + jseg];
  dst[0] = o0.v;
  dst[1] = o1.v;
}

// ---- pass B, j-split 5, i-tile 32/wave (R9).
__global__ __launch_bounds__(128, 2) void k_nl(
    const __hip_bfloat16* __restrict__ th, const __hip_bfloat16* __restrict__ ph,
    const __hip_bfloat16* __restrict__ gT, ushort* __restrict__ py) {
  const int js = blockIdx.y, b = blockIdx.z;
  const int lane = threadIdx.x & 63, w = threadIdx.x >> 6;
  const int il = lane & 15, hi = lane >> 4;
  const int itile32 = blockIdx.x * 2 + w;
  const int i0w = itile32 * 32;
  const int jstart = js * 1280;
  const int jbase = ((il >> 2) << 3) + (il & 3);  // sigma(row=il)

  __shared__ __align__(16) ushort bufA[8192], bufB[8192];

  const __hip_bfloat16* phB = ph + (size_t)b * kN * kC;
  const __hip_bfloat16* gTB = gT + (size_t)b * kC * kN;

  const size_t tr0 = ((size_t)b * kN + i0w + il) * kC;
  const size_t tr1 = ((size_t)b * kN + i0w + 16 + il) * kC;
  const short8 tA0k0 = *(const short8*)&th[tr0 + hi * 8];
  const short8 tA0k1 = *(const short8*)&th[tr0 + 32 + hi * 8];
  const short8 tA1k0 = *(const short8*)&th[tr1 + hi * 8];
  const short8 tA1k1 = *(const short8*)&th[tr1 + 32 + hi * 8];

  const int f0 = 4 * w;
  const char* sp[4];
  const char* sg[4];
#pragma unroll
  for (int k = 0; k < 4; ++k) {
    const int f = f0 + k;
    const int pr = jstart + jbase + ((f >> 1) & 1) * 4 + ((f >> 2) & 1) * 32;
    const int pc = (f & 1) * 32 + hi * 8;
    sp[k] = (const char*)&phB[(size_t)pr * kC + pc];
    const int gc = (f & 3) * 16 + il;
    const int gj = jstart + ((f >> 2) & 1) * 32 + hi * 8;
    sg[k] = (const char*)&gTB[(size_t)gc * kN + gj];
  }

#define NLSTAGE(DST)                                                        \
  {                                                                         \
    _Pragma("unroll") for (int k = 0; k < 4; ++k) {                         \
      GL16(sp[k], &DST[(f0 + k) * 512]);                                    \
      GL16(sg[k], &DST[4096 + (f0 + k) * 512]);                             \
      sp[k] += (size_t)64 * kC * 2;                                         \
      sg[k] += (size_t)64 * 2;                                              \
    }                                                                       \
  }

#define QKI(TB0, TB1, s0, s1, s2, s3)                                        \
    f32x4 s0 = {0.f, 0.f, 0.f, 0.f};                                         \
    f32x4 s1 = {0.f, 0.f, 0.f, 0.f};                                         \
    f32x4 s2 = {0.f, 0.f, 0.f, 0.f};                                         \
    f32x4 s3 = {0.f, 0.f, 0.f, 0.f};                                         \
    s0 = __builtin_amdgcn_mfma_f32_16x16x32_bf16(pa0, TB0, s0, 0, 0, 0);     \
    s0 = __builtin_amdgcn_mfma_f32_16x16x32_bf16(pa1, TB1, s0, 0, 0, 0);     \
    s1 = __builtin_amdgcn_mfma_f32_16x16x32_bf16(pa2, TB0, s1, 0, 0, 0);     \
    s1 = __builtin_amdgcn_mfma_f32_16x16x32_bf16(pa3, TB1, s1, 0, 0, 0);     \
    s2 = __builtin_amdgcn_mfma_f32_16x16x32_bf16(pa4, TB0, s2, 0, 0, 0);     \
    s2 = __builtin_amdgcn_mfma_f32_16x16x32_bf16(pa5, TB1, s2, 0, 0, 0);     \
    s3 = __builtin_amdgcn_mfma_f32_16x16x32_bf16(pa6, TB0, s3, 0, 0, 0);     \
    s3 = __builtin_amdgcn_mfma_f32_16x16x32_bf16(pa7, TB1, s3, 0, 0, 0);

#define PACK2(sa, sb, pb)                                                    \
    short8 pb;                                                               \
    {                                                                        \
      uint* pw_ = (uint*)&pb;                                                \
      pw_[0] = pkbf(exp2f(fmaf(sa[0], kLOG2E, -kSHIFT)),                     \
                    exp2f(fmaf(sa[1], kLOG2E, -kSHIFT)));                    \
      pw_[1] = pkbf(exp2f(fmaf(sa[2], kLOG2E, -kSHIFT)),                     \
                    exp2f(fmaf(sa[3], kLOG2E, -kSHIFT)));                    \
      pw_[2] = pkbf(exp2f(fmaf(sb[0], kLOG2E, -kSHIFT)),                     \
                    exp2f(fmaf(sb[1], kLOG2E, -kSHIFT)));                    \
      pw_[3] = pkbf(exp2f(fmaf(sb[2], kLOG2E, -kSHIFT)),                     \
                    exp2f(fmaf(sb[3], kLOG2E, -kSHIFT)));                    \
    }

#define NLCOMP(SRC)                                                          \
  {                                                                          \
    const ushort* bp_ = SRC;                                                 \
    const short8 pa0 = *(const short8*)&bp_[0 * 512 + lane * 8];             \
    const short8 pa1 = *(const short8*)&bp_[1 * 512 + lane * 8];             \
    const short8 pa2 = *(const short8*)&bp_[2 * 512 + lane * 8];             \
    const short8 pa3 = *(const short8*)&bp_[3 * 512 + lane * 8];             \
    const short8 pa4 = *(const short8*)&bp_[4 * 512 + lane * 8];             \
    const short8 pa5 = *(const short8*)&bp_[5 * 512 + lane * 8];             \
    const short8 pa6 = *(const short8*)&bp_[6 * 512 + lane * 8];             \
    const short8 pa7 = *(const short8*)&bp_[7 * 512 + lane * 8];             \
    const short8 ga0 = *(const short8*)&bp_[4096 + 0 * 512 + lane * 8];      \
    const short8 ga1 = *(const short8*)&bp_[4096 + 1 * 512 + lane * 8];      \
    const short8 ga2 = *(const short8*)&bp_[4096 + 2 * 512 + lane * 8];      \
    const short8 ga3 = *(const short8*)&bp_[4096 + 3 * 512 + lane * 8];      \
    const short8 ga4 = *(const short8*)&bp_[4096 + 4 * 512 + lane * 8];      \
    const short8 ga5 = *(const short8*)&bp_[4096 + 5 * 512 + lane * 8];      \
    const short8 ga6 = *(const short8*)&bp_[4096 + 6 * 512 + lane * 8];      \
    const short8 ga7 = *(const short8*)&bp_[4096 + 7 * 512 + lane * 8];      \
    {                                                                        \
      QKI(tA0k0, tA0k1, s00, s01, s02, s03)                                  \
      PACK2(s00, s01, pb00)                                                  \
      PACK2(s02, s03, pb01)                                                  \
      ay00 = __builtin_amdgcn_mfma_f32_16x16x32_bf16(ga0, pb00, ay00, 0, 0, 0);\
      ay01 = __builtin_amdgcn_mfma_f32_16x16x32_bf16(ga1, pb00, ay01, 0, 0, 0);\
      ay02 = __builtin_amdgcn_mfma_f32_16x16x32_bf16(ga2, pb00, ay02, 0, 0, 0);\
      ay03 = __builtin_amdgcn_mfma_f32_16x16x32_bf16(ga3, pb00, ay03, 0, 0, 0);\
      ay00 = __builtin_amdgcn_mfma_f32_16x16x32_bf16(ga4, pb01, ay00, 0, 0, 0);\
      ay01 = __builtin_amdgcn_mfma_f32_16x16x32_bf16(ga5, pb01, ay01, 0, 0, 0);\
      ay02 = __builtin_amdgcn_mfma_f32_16x16x32_bf16(ga6, pb01, ay02, 0, 0, 0);\
      ay03 = __builtin_amdgcn_mfma_f32_16x16x32_bf16(ga7, pb01, ay03, 0, 0, 0);\
    }                                                                        \
    {                                                                        \
      QKI(tA1k0, tA1k1, s10, s11, s12, s13)                                  \
      PACK2(s10, s11, pb10)                                                  \
      PACK2(s12, s13, pb11)                                                  \
      ay10 = __builtin_amdgcn_mfma_f32_16x16x32_bf16(ga0, pb10, ay10, 0, 0, 0);\
      ay11 = __builtin_amdgcn_mfma_f32_16x16x32_bf16(ga1, pb10, ay11, 0, 0, 0);\
      ay12 = __builtin_amdgcn_mfma_f32_16x16x32_bf16(ga2, pb10, ay12, 0, 0, 0);\
      ay13 = __builtin_amdgcn_mfma_f32_16x16x32_bf16(ga3, pb10, ay13, 0, 0, 0);\
      ay10 = __builtin_amdgcn_mfma_f32_16x16x32_bf16(ga4, pb11, ay10, 0, 0, 0);\
      ay11 = __builtin_amdgcn_mfma_f32_16x16x32_bf16(ga5, pb11, ay11, 0, 0, 0);\
      ay12 = __builtin_amdgcn_mfma_f32_16x16x32_bf16(ga6, pb11, ay12, 0, 0, 0);\
      ay13 = __builtin_amdgcn_mfma_f32_16x16x32_bf16(ga7, pb11, ay13, 0, 0, 0);\
    }                                                                        \
  }

  f32x4 ay00 = {0.f, 0.f, 0.f, 0.f}, ay01 = {0.f, 0.f, 0.f, 0.f};
  f32x4 ay02 = {0.f, 0.f, 0.f, 0.f}, ay03 = {0.f, 0.f, 0.f, 0.f};
  f32x4 ay10 = {0.f, 0.f, 0.f, 0.f}, ay11 = {0.f, 0.f, 0.f, 0.f};
  f32x4 ay12 = {0.f, 0.f, 0.f, 0.f}, ay13 = {0.f, 0.f, 0.f, 0.f};

  NLSTAGE(bufA);
  __syncthreads();
#pragma unroll 1
  for (int t = 0; t < 9; ++t) {
    NLSTAGE(bufB);
    NLCOMP(bufA);
    __syncthreads();
    NLSTAGE(bufA);
    NLCOMP(bufB);
    __syncthreads();
  }
  NLSTAGE(bufB);
  NLCOMP(bufA);
  __syncthreads();
  NLCOMP(bufB);
#undef NLSTAGE
#undef NLCOMP
#undef QKI
#undef PACK2

  uint* b32 = (uint*)(py + ((size_t)(js * kB + b) * (kN / 32) + itile32) * 2048);
  b32[0 * 64 + lane] = pkbf(ay00[0], ay00[1]);
  b32[1 * 64 + lane] = pkbf(ay00[2], ay00[3]);
  b32[2 * 64 + lane] = pkbf(ay01[0], ay01[1]);
  b32[3 * 64 + lane] = pkbf(ay01[2], ay01[3]);
  b32[4 * 64 + lane] = pkbf(ay02[0], ay02[1]);
  b32[5 * 64 + lane] = pkbf(ay02[2], ay02[3]);
  b32[6 * 64 + lane] = pkbf(ay03[0], ay03[1]);
  b32[7 * 64 + lane] = pkbf(ay03[2], ay03[3]);
  b32[8 * 64 + lane] = pkbf(ay10[0], ay10[1]);
  b32[9 * 64 + lane] = pkbf(ay10[2], ay10[3]);
  b32[10 * 64 + lane] = pkbf(ay11[0], ay11[1]);
  b32[11 * 64 + lane] = pkbf(ay11[2], ay11[3]);
  b32[12 * 64 + lane] = pkbf(ay12[0], ay12[1]);
  b32[13 * 64 + lane] = pkbf(ay12[2], ay12[3]);
  b32[14 * 64 + lane] = pkbf(ay13[0], ay13[1]);
  b32[15 * 64 + lane] = pkbf(ay13[2], ay13[3]);
}

// ---- reduce 5 partials + fused W_y + residuals -> z bf16 pixel-major.
__global__ __launch_bounds__(128) void k_wy(
    const ushort* __restrict__ py, const __hip_bfloat16* __restrict__ wWb,
    const float* __restrict__ x1, const float* __restrict__ alphap,
    ushort* __restrict__ zb) {
  const int b = blockIdx.y;
  const int lane = threadIdx.x & 63, w = threadIdx.x >> 6;
  const int il = lane & 15, hi = lane >> 4;
  const int itile32 = blockIdx.x * 2 + w;
  const int i0w = itile32 * 32;

  __shared__ __align__(16) ushort yt2[2][32 * 72];
  __shared__ __align__(16) ushort zt2[2][32 * 72];
  ushort* yt = yt2[w];
  ushort* zt = zt2[w];

  const uint* p[5];
#pragma unroll
  for (int s = 0; s < 5; ++s)
    p[s] = (const uint*)(py + ((size_t)(s * kB + b) * (kN / 32) + itile32) * 2048);

#pragma unroll
  for (int k = 0; k < 16; ++k) {
    float lo = 0.f, hs = 0.f;
#pragma unroll
    for (int s = 0; s < 5; ++s) {
      const uint u = p[s][k * 64 + lane];
      lo += __uint_as_float(u << 16);
      hs += __uint_as_float(u & 0xffff0000u);
    }
    const int row = (k >> 3) * 16 + il;
    const int col = ((k >> 1) & 3) * 16 + hi * 4 + (k & 1) * 2;
    *(uint*)&yt[row * 72 + col] = pkbf(lo, hs);
  }

  const float alpha = alphap[0];
#pragma unroll
  for (int a = 0; a < 2; ++a) {
    const short8 by0 = *(const short8*)&yt[(a * 16 + il) * 72 + hi * 8];
    const short8 by1 = *(const short8*)&yt[(a * 16 + il) * 72 + 32 + hi * 8];
#pragma unroll
    for (int q = 0; q < 4; ++q) {
      const short8 af0 = *(const short8*)&wWb[(size_t)(q * 16 + il) * kC + hi * 8];
      const short8 af1 = *(const short8*)&wWb[(size_t)(q * 16 + il) * kC + 32 + hi * 8];
      f32x4 o4 = {0.f, 0.f, 0.f, 0.f};
      o4 = __builtin_amdgcn_mfma_f32_16x16x32_bf16(af0, by0, o4, 0, 0, 0);
      o4 = __builtin_amdgcn_mfma_f32_16x16x32_bf16(af1, by1, o4, 0, 0, 0);
      float zv[4];
#pragma unroll
      for (int r = 0; r < 4; ++r) {
        const int o = q * 16 + hi * 4 + r;
        const size_t idx = ((size_t)b * kC + o) * kN + i0w + a * 16 + il;
        const float xv = x1[idx];
        const float pr = xv >= 0.f ? xv : alpha * xv;
        zv[r] = o4[r] + pr + xv;
      }
      *(uint*)&zt[(a * 16 + il) * 72 + q * 16 + hi * 4] = pkbf(zv[0], zv[1]);
      *(uint*)&zt[(a * 16 + il) * 72 + q * 16 + hi * 4 + 2] = pkbf(zv[2], zv[3]);
    }
  }

  // wave-local transpose out (same-wave LDS RAW -> no barrier needed)
  const int px = lane >> 1, cseg = (lane & 1) * 32;
  short8* d = (short8*)&zb[((size_t)b * kN + i0w + px) * kC + cseg];
#pragma unroll
  for (int k = 0; k < 4; ++k)
    d[k] = *(const short8*)&zt[px * 72 + cseg + k * 8];
}

extern "C" void kernel_launch(void* const* d_in, const int* in_sizes, int n_in,
                              void* d_out, int out_size, void* d_ws, size_t ws_size,
                              hipStream_t stream) {
  const float* x      = (const float*)d_in[0];
  const float* w1     = (const float*)d_in[1];
  const float* w2     = (const float*)d_in[2];
  const float* wg     = (const float*)d_in[3];
  const float* wth    = (const float*)d_in[4];
  const float* wph    = (const float*)d_in[5];
  const float* wWm    = (const float*)d_in[6];
  const float* alphap = (const float*)d_in[7];
  float* out = (float*)d_out;

  const size_t SZ = (size_t)kB * kC * kN;  // 819200
  float* x1 = (float*)d_ws;                              // [B][C][N] f32
  __hip_bfloat16* pTb = (__hip_bfloat16*)(x1 + SZ);      // [B][N][C] bf16
  __hip_bfloat16* phb = pTb + SZ;
  __hip_bfloat16* gb  = phb + SZ;                        // later reused as zb
  __hip_bfloat16* gT  = gb + SZ;
  float* partial = (float*)(gT + SZ);                    // [B][5][N] f32
  ushort* wc1 = (ushort*)(partial + (size_t)kB * 5 * kN);
  ushort* wc2 = wc1 + 9 * kC * kC;
  __hip_bfloat16* Mb  = (__hip_bfloat16*)(wc2 + 9 * kC * kC);
  __hip_bfloat16* wgb = Mb + kC * kC;
  __hip_bfloat16* wWb = wgb + kC * kC;
  ushort* py = (ushort*)(wWb + kC * kC);                 // 5*B*(N/32)*2048
  ushort* xb = py;                                       // overlay: dead before k_nl
  ushort* zb = (ushort*)gb;                              // overlay: gb dead after gscale

  k_prep<<<144, 256, 0, stream>>>(w1, w2, wc1, wc2);
  k_prepM<<<16, 256, 0, stream>>>(wth, wph, wg, wWm, Mb, wgb, wWb);
  k_tobf<<<dim3(kN / 64, kB), 256, 0, stream>>>(x, xb);
  k_convm<0><<<dim3(400, kB), 256, 0, stream>>>(xb, wc1, alphap, x1, (ushort*)pTb);
  k_pw<<<dim3(kN / 16, kB), 256, 0, stream>>>(pTb, Mb, wgb, phb, gb);
  k_colstat<<<dim3(kN / 64, 5, kB), 128, 0, stream>>>(pTb, phb, partial);
  k_gscale<<<dim3(kN / 64, kB), 256, 0, stream>>>(gb, partial, gT);
  k_nl<<<dim3(kN / 64, 5, kB), 128, 0, stream>>>(pTb, phb, gT, py);
  k_wy<<<dim3(kN / 64, kB), 128, 0, stream>>>(py, wWb, x1, alphap, zb);
  k_convm<1><<<dim3(400, kB), 256, 0, stream>>>(zb, wc2, alphap, out, nullptr);
}